// Round 3
// baseline (4623.232 us; speedup 1.0000x reference)
//
#include <hip/hip_runtime.h>
#include <hip/hip_bf16.h>
#include <math.h>

#define BATCH 16384
#define HDIM  512
#define VOCAB 32
#define STEPS 20
#define G4    (4 * HDIM)   // 2048

typedef _Float16 f16;
typedef _Float16 f16x8 __attribute__((ext_vector_type(8)));
typedef _Float16 f16x4 __attribute__((ext_vector_type(4)));
typedef float    f32x4 __attribute__((ext_vector_type(4)));
typedef float    f32x16 __attribute__((ext_vector_type(16)));

#define SH   256.0f            // h pre-scale before fp16 split
#define SW   1024.0f           // W pre-scale before fp16 split
#define SINV (1.0f / (SH * SW))
#define HINV (1.0f / SH)

// ---------------------------------------------------------------------------
// async global->LDS (16B per lane); LDS dst must be wave-uniform base + lane*16
// ---------------------------------------------------------------------------
__device__ __forceinline__ void gload16(const void* g, void* l) {
#if defined(__has_builtin) && __has_builtin(__builtin_amdgcn_global_load_lds)
    __builtin_amdgcn_global_load_lds(
        (const __attribute__((address_space(1))) void*)g,
        (__attribute__((address_space(3))) void*)l, 16, 0, 0);
#else
    *(float4*)l = *(const float4*)g;
#endif
}

// ---------------------------------------------------------------------------
// init kernels
// ---------------------------------------------------------------------------
__global__ void init_xb_kernel(const float* __restrict__ W_ih,
                               const float* __restrict__ b_ih,
                               const float* __restrict__ b_hh,
                               const float* __restrict__ x0,
                               float* __restrict__ xb) {
    int n = blockIdx.x * blockDim.x + threadIdx.x;
    if (n >= G4) return;
    float s = b_ih[n] + b_hh[n];
    const float* wr = W_ih + (size_t)n * VOCAB;
    #pragma unroll
    for (int v = 0; v < VOCAB; v++) s += wr[v] * x0[v];
    xb[n] = s;
}

__global__ void init_mask_kernel(float* __restrict__ mask) {
    int b = blockIdx.x * blockDim.x + threadIdx.x;
    if (b < BATCH) mask[b] = 1.0f;
}

// split scaled fp32 -> (hi, lo) fp16 pair
__global__ void split_kernel(const float* __restrict__ src, float scale,
                             f16* __restrict__ hi, f16* __restrict__ lo,
                             int n) {
    int i = blockIdx.x * blockDim.x + threadIdx.x;
    if (i >= n) return;
    float x = src[i] * scale;
    f16 h = (f16)x;
    f16 l = (f16)(x - (float)h);
    hi[i] = h;
    lo[i] = l;
}

// ---------------------------------------------------------------------------
// MFMA GEMM (gates = h @ W_hh^T, 3-pass fp16 split) + fused LSTM cell.
// Block tile: 256 m x 128 n_local, n_local = gate*32 + jj (gate-major).
// 4 waves stacked on m: wave tile = 64 m x 128 n (2 mtiles x 4 gate-tiles).
// mfma_f32_32x32x16_f16 layouts:
//   A: lane holds A[m = lane&31][k = (lane>>5)*8 + j]
//   B: lane holds B[k = (lane>>5)*8 + j][n = lane&31]
//   D: lane holds D[row = (reg&3)+8*(reg>>2)+4*(lane>>5)][col = lane&31]
//      (m74/m101-verified)
// ---------------------------------------------------------------------------
__global__ __launch_bounds__(256)
void gemm_cell_mfma(const f16* __restrict__ hhi, const f16* __restrict__ hlo,
                    f16* __restrict__ hhi_o,  f16* __restrict__ hlo_o,
                    float* __restrict__ c,
                    const f16* __restrict__ Wh, const f16* __restrict__ Wl,
                    const float* __restrict__ xb) {
    __shared__ f16 Ah[256 * 32];   // 16 KB
    __shared__ f16 Al[256 * 32];   // 16 KB
    __shared__ f16 Bh[128 * 32];   // 8 KB
    __shared__ f16 Bl[128 * 32];   // 8 KB

    const int tid  = threadIdx.x;
    const int lane = tid & 63;
    const int wm   = tid >> 6;        // wave id = m quarter (0..3)
    const int m0   = blockIdx.x * 256;
    const int j0   = blockIdx.y * 32;

    f32x16 acc[2][4];                 // [mtile][gate]
    #pragma unroll
    for (int a = 0; a < 2; a++)
        #pragma unroll
        for (int b = 0; b < 4; b++)
            #pragma unroll
            for (int r = 0; r < 16; r++) acc[a][b][r] = 0.0f;

    // staging geometry: thread covers LDS row (seg*64 + tid>>2), 16B granule cc
    const int r0 = tid >> 2;            // 0..63
    const int cc = (tid & 3) * 8;       // f16 offset of 16B granule
    // W source rows for B-tile LDS rows r0 and r0+64 (n_local -> gate*512+j)
    const int wr0 = ((r0) >> 5) * HDIM + j0 + (r0 & 31);
    const int wr1 = ((r0 + 64) >> 5) * HDIM + j0 + ((r0 + 64) & 31);

    const int half = lane >> 5;         // k half for A/B operands
    const int l31  = lane & 31;

    for (int k0 = 0; k0 < HDIM; k0 += 32) {
        __syncthreads();   // previous tile's frag reads done before overwrite
        #pragma unroll
        for (int s = 0; s < 4; s++) {
            int r = s * 64 + r0;
            gload16(hhi + (size_t)(m0 + r) * HDIM + k0 + cc, &Ah[r * 32 + cc]);
            gload16(hlo + (size_t)(m0 + r) * HDIM + k0 + cc, &Al[r * 32 + cc]);
        }
        gload16(Wh + (size_t)wr0 * HDIM + k0 + cc, &Bh[r0 * 32 + cc]);
        gload16(Wh + (size_t)wr1 * HDIM + k0 + cc, &Bh[(r0 + 64) * 32 + cc]);
        gload16(Wl + (size_t)wr0 * HDIM + k0 + cc, &Bl[r0 * 32 + cc]);
        gload16(Wl + (size_t)wr1 * HDIM + k0 + cc, &Bl[(r0 + 64) * 32 + cc]);
        __syncthreads();   // drains vmcnt -> LDS tile ready

        #pragma unroll
        for (int ks = 0; ks < 2; ks++) {
            const int koff = ks * 16 + half * 8;
            f16x8 ah0 = *(const f16x8*)&Ah[(wm * 64 +      l31) * 32 + koff];
            f16x8 ah1 = *(const f16x8*)&Ah[(wm * 64 + 32 + l31) * 32 + koff];
            f16x8 al0 = *(const f16x8*)&Al[(wm * 64 +      l31) * 32 + koff];
            f16x8 al1 = *(const f16x8*)&Al[(wm * 64 + 32 + l31) * 32 + koff];
            #pragma unroll
            for (int g = 0; g < 4; g++) {
                f16x8 bh = *(const f16x8*)&Bh[(g * 32 + l31) * 32 + koff];
                f16x8 bl = *(const f16x8*)&Bl[(g * 32 + l31) * 32 + koff];
                acc[0][g] = __builtin_amdgcn_mfma_f32_32x32x16_f16(ah0, bh, acc[0][g], 0, 0, 0);
                acc[1][g] = __builtin_amdgcn_mfma_f32_32x32x16_f16(ah1, bh, acc[1][g], 0, 0, 0);
                acc[0][g] = __builtin_amdgcn_mfma_f32_32x32x16_f16(ah0, bl, acc[0][g], 0, 0, 0);
                acc[1][g] = __builtin_amdgcn_mfma_f32_32x32x16_f16(ah1, bl, acc[1][g], 0, 0, 0);
                acc[0][g] = __builtin_amdgcn_mfma_f32_32x32x16_f16(al0, bh, acc[0][g], 0, 0, 0);
                acc[1][g] = __builtin_amdgcn_mfma_f32_32x32x16_f16(al1, bh, acc[1][g], 0, 0, 0);
            }
        }
    }

    // epilogue: lane owns all 4 gates for 2x16 (m, j) pairs -> fused cell
    const int j = j0 + l31;
    const float xbi = xb[0 * HDIM + j];
    const float xbf = xb[1 * HDIM + j];
    const float xbg = xb[2 * HDIM + j];
    const float xbo = xb[3 * HDIM + j];
    #pragma unroll
    for (int mt = 0; mt < 2; mt++) {
        #pragma unroll
        for (int reg = 0; reg < 16; reg++) {
            int row = (reg & 3) + 8 * (reg >> 2) + 4 * half;
            int m = m0 + wm * 64 + mt * 32 + row;
            float gi = acc[mt][0][reg] * SINV + xbi;
            float gf = acc[mt][1][reg] * SINV + xbf;
            float gg = acc[mt][2][reg] * SINV + xbg;
            float go = acc[mt][3][reg] * SINV + xbo;
            float si = 1.0f / (1.0f + expf(-gi));
            float sf = 1.0f / (1.0f + expf(-gf));
            float tg = tanhf(gg);
            float so = 1.0f / (1.0f + expf(-go));
            size_t idx = (size_t)m * HDIM + j;
            float cn = sf * c[idx] + si * tg;
            c[idx] = cn;
            float hv = so * tanhf(cn);
            float hs = hv * SH;
            f16 hh = (f16)hs;
            f16 hl = (f16)(hs - (float)hh);
            hhi_o[idx] = hh;
            hlo_o[idx] = hl;
        }
    }
}

// ---------------------------------------------------------------------------
// Per-step output: logits = h @ W_out^T + b_out (V=32), argmax/softmax,
// one-hot message, mask bookkeeping, per-block log-prob partial.
// h reconstructed from split pair: h = (hh + hl) / SH.
// ---------------------------------------------------------------------------
__global__ __launch_bounds__(256)
void out_step_kernel(const f16* __restrict__ hhi, const f16* __restrict__ hlo,
                     const float* __restrict__ W_out,
                     const float* __restrict__ b_out,
                     float* __restrict__ mask,
                     float* __restrict__ msg_t,
                     float* __restrict__ maskout_t,
                     float* __restrict__ lp_part,
                     const int* __restrict__ eos_ptr) {
    __shared__ __align__(16) float hs[8][128];
    __shared__ float ws[128][32];
    __shared__ float red[8];

    const int tid = threadIdx.x;
    const int v   = tid & 31;
    const int bb  = tid >> 5;          // 0..7
    const int b0  = blockIdx.x * 8;
    const int eos = *eos_ptr;

    float logit = 0.0f;
    for (int k0 = 0; k0 < HDIM; k0 += 128) {
        __syncthreads();
        {   // stage h: 8 rows x 128 k
            size_t base = (size_t)(b0 + bb) * HDIM + k0 + v * 4;
            f16x4 a = *(const f16x4*)(hhi + base);
            f16x4 b = *(const f16x4*)(hlo + base);
            #pragma unroll
            for (int i = 0; i < 4; i++)
                hs[bb][v * 4 + i] = ((float)a[i] + (float)b[i]) * HINV;
        }
        {   // stage W_out transposed
            int kk = bb * 16;
            const float* src = W_out + (size_t)v * HDIM + k0 + kk;
            float4 q0 = *(const float4*)(src + 0);
            float4 q1 = *(const float4*)(src + 4);
            float4 q2 = *(const float4*)(src + 8);
            float4 q3 = *(const float4*)(src + 12);
            ws[kk + 0][v] = q0.x;  ws[kk + 1][v] = q0.y;
            ws[kk + 2][v] = q0.z;  ws[kk + 3][v] = q0.w;
            ws[kk + 4][v] = q1.x;  ws[kk + 5][v] = q1.y;
            ws[kk + 6][v] = q1.z;  ws[kk + 7][v] = q1.w;
            ws[kk + 8][v] = q2.x;  ws[kk + 9][v] = q2.y;
            ws[kk + 10][v] = q2.z; ws[kk + 11][v] = q2.w;
            ws[kk + 12][v] = q3.x; ws[kk + 13][v] = q3.y;
            ws[kk + 14][v] = q3.z; ws[kk + 15][v] = q3.w;
        }
        __syncthreads();
        #pragma unroll
        for (int k = 0; k < 128; k++)
            logit = fmaf(hs[bb][k], ws[k][v], logit);
    }
    logit += b_out[v];

    // argmax over 32 lanes, first-index tie-break (np.argmax semantics)
    float mval = logit;
    int   midx = v;
    #pragma unroll
    for (int off = 16; off > 0; off >>= 1) {
        float ov = __shfl_xor(mval, off, 32);
        int   oi = __shfl_xor(midx, off, 32);
        if (ov > mval || (ov == mval && oi < midx)) { mval = ov; midx = oi; }
    }
    float s = expf(logit - mval);
    #pragma unroll
    for (int off = 16; off > 0; off >>= 1) s += __shfl_xor(s, off, 32);

    const int b = b0 + bb;
    msg_t[(size_t)b * VOCAB + v] = (v == midx) ? 1.0f : 0.0f;
    if (v == 0) {
        float mo = mask[b];
        maskout_t[b] = mo;
        red[bb] = mo * (-logf(s));    // log softmax at argmax = -log(sum)
        if (midx == eos) mask[b] = 0.0f;
    }
    __syncthreads();
    if (tid == 0) {
        float t = 0.0f;
        #pragma unroll
        for (int i = 0; i < 8; i++) t += red[i];
        lp_part[blockIdx.x] = t;
    }
}

__global__ void reduce_lp_kernel(const float* __restrict__ parts, int n,
                                 float* __restrict__ out) {
    __shared__ float sm[256];
    float s = 0.0f;
    for (int i = threadIdx.x; i < n; i += 256) s += parts[i];
    sm[threadIdx.x] = s;
    __syncthreads();
    for (int off = 128; off > 0; off >>= 1) {
        if (threadIdx.x < off) sm[threadIdx.x] += sm[threadIdx.x + off];
        __syncthreads();
    }
    if (threadIdx.x == 0) *out = sm[0];
}

// ---------------------------------------------------------------------------
extern "C" void kernel_launch(void* const* d_in, const int* in_sizes, int n_in,
                              void* d_out, int out_size, void* d_ws, size_t ws_size,
                              hipStream_t stream) {
    const float* enc_h  = (const float*)d_in[0];
    const float* enc_c  = (const float*)d_in[1];
    const float* W_ih   = (const float*)d_in[2];
    const float* b_ih   = (const float*)d_in[3];
    const float* W_hh   = (const float*)d_in[4];
    const float* b_hh   = (const float*)d_in[5];
    const float* W_out  = (const float*)d_in[6];
    const float* b_out  = (const float*)d_in[7];
    const float* x0     = (const float*)d_in[8];
    const int*   eosP   = (const int*)d_in[9];

    float* out     = (float*)d_out;
    float* msg     = out;                                   // [20,16384,32]
    float* maskout = out + (size_t)STEPS * BATCH * VOCAB;   // [20,1,16384]
    float* lp_out  = maskout + (size_t)STEPS * BATCH;       // scalar

    // workspace layout
    const size_t NH = (size_t)BATCH * HDIM;                 // 8388608
    char* w = (char*)d_ws;
    f16* hhi_a = (f16*)w;            w += NH * sizeof(f16);
    f16* hlo_a = (f16*)w;            w += NH * sizeof(f16);
    f16* hhi_b = (f16*)w;            w += NH * sizeof(f16);
    f16* hlo_b = (f16*)w;            w += NH * sizeof(f16);
    float* cbuf = (float*)w;         w += NH * sizeof(float);
    f16* Wsh = (f16*)w;              w += (size_t)G4 * HDIM * sizeof(f16);
    f16* Wsl = (f16*)w;              w += (size_t)G4 * HDIM * sizeof(f16);
    float* xb = (float*)w;           w += G4 * sizeof(float);
    float* maskbuf = (float*)w;      w += BATCH * sizeof(float);
    float* lp_parts = (float*)w;     // STEPS * (BATCH/8) floats

    hipMemcpyAsync(cbuf, enc_c, NH * sizeof(float), hipMemcpyDeviceToDevice, stream);
    init_mask_kernel<<<(BATCH + 255) / 256, 256, 0, stream>>>(maskbuf);
    init_xb_kernel<<<(G4 + 255) / 256, 256, 0, stream>>>(W_ih, b_ih, b_hh, x0, xb);
    split_kernel<<<((int)(G4 * HDIM) + 255) / 256, 256, 0, stream>>>(
        W_hh, SW, Wsh, Wsl, G4 * HDIM);
    split_kernel<<<((int)NH + 255) / 256, 256, 0, stream>>>(
        enc_h, SH, hhi_a, hlo_a, (int)NH);

    for (int t = 0; t < STEPS; t++) {
        const f16* hi_in = (t & 1) ? hhi_b : hhi_a;
        const f16* lo_in = (t & 1) ? hlo_b : hlo_a;
        f16* hi_out      = (t & 1) ? hhi_a : hhi_b;
        f16* lo_out      = (t & 1) ? hlo_a : hlo_b;
        gemm_cell_mfma<<<dim3(BATCH / 256, HDIM / 32), 256, 0, stream>>>(
            hi_in, lo_in, hi_out, lo_out, cbuf, Wsh, Wsl, xb);
        out_step_kernel<<<BATCH / 8, 256, 0, stream>>>(
            hi_out, lo_out, W_out, b_out, maskbuf,
            msg + (size_t)t * BATCH * VOCAB,
            maskout + (size_t)t * BATCH,
            lp_parts + (size_t)t * (BATCH / 8),
            eosP);
    }
    reduce_lp_kernel<<<1, 256, 0, stream>>>(lp_parts, STEPS * (BATCH / 8), lp_out);
}

// Round 4
// 4294.991 us; speedup vs baseline: 1.0764x; 1.0764x over previous
//
#include <hip/hip_runtime.h>
#include <math.h>

#define BATCH 16384
#define HDIM  512
#define VOCAB 32
#define STEPS 20
#define G4    2048

typedef _Float16 f16;
typedef _Float16 f16x8 __attribute__((ext_vector_type(8)));
typedef float    f32x16 __attribute__((ext_vector_type(16)));

#define SH   256.0f            // h pre-scale before fp16 split
#define SW   1024.0f           // W pre-scale before fp16 split
#define SINV (1.0f / (SH * SW))
#define HINV (1.0f / SH)

// Fragment-ordered global images (granule = 16 B = 8 f16 = one lane's A/B frag):
//  hT  [kk:32][mb:512][lane:64]          kk = k/16, granule(kk,mb,lane) =
//        h[m = mb*32 + (lane&31)][k = kk*16 + (lane>>5)*8 .. +8]
//  Wimg[jb:16][kc:16][ks:2][g:4][lane:64] granule =
//        W[n = g*512 + jb*32 + (lane&31)][k = kc*32 + ks*16 + (lane>>5)*8 .. +8]

__device__ __forceinline__ void gload16(const void* g, void* l) {
#if defined(__has_builtin) && __has_builtin(__builtin_amdgcn_global_load_lds)
    __builtin_amdgcn_global_load_lds(
        (const __attribute__((address_space(1))) void*)g,
        (__attribute__((address_space(3))) void*)l, 16, 0, 0);
#else
    *(float4*)l = *(const float4*)g;
#endif
}

// ---------------------------------------------------------------------------
// init / prep kernels (once per launch, outside the step loop)
// ---------------------------------------------------------------------------
__global__ void init_xb_kernel(const float* __restrict__ W_ih,
                               const float* __restrict__ b_ih,
                               const float* __restrict__ b_hh,
                               const float* __restrict__ x0,
                               float* __restrict__ xb) {
    int n = blockIdx.x * blockDim.x + threadIdx.x;
    if (n >= G4) return;
    float s = b_ih[n] + b_hh[n];
    const float* wr = W_ih + (size_t)n * VOCAB;
    #pragma unroll
    for (int v = 0; v < VOCAB; v++) s += wr[v] * x0[v];
    xb[n] = s;
}

__global__ void init_mask_kernel(float* __restrict__ mask) {
    int b = blockIdx.x * blockDim.x + threadIdx.x;
    if (b < BATCH) mask[b] = 1.0f;
}

// W_hh (fp32 [2048][512]) -> fragment-ordered split images (131072 granules)
__global__ void wimg_kernel(const float* __restrict__ W_hh,
                            f16* __restrict__ Wh, f16* __restrict__ Wl) {
    size_t g  = (size_t)blockIdx.x * 256 + threadIdx.x;   // granule id
    int ln = g & 63;  size_t r = g >> 6;                   // r = ((jb*16+kc)*2+ks)*4+gg
    int gg = r & 3;   size_t r2 = r >> 2;
    int ks = r2 & 1;  size_t r3 = r2 >> 1;
    int kc = r3 & 15; int jb = (int)(r3 >> 4);
    int n = gg * 512 + jb * 32 + (ln & 31);
    int k = kc * 32 + ks * 16 + (ln >> 5) * 8;
    const float* s = W_hh + (size_t)n * HDIM + k;
    f16x8 vh, vl;
    #pragma unroll
    for (int i = 0; i < 8; i++) {
        float x = s[i] * SW;
        f16 h = (f16)x;
        vh[i] = h;
        vl[i] = (f16)(x - (float)h);
    }
    *(f16x8*)(Wh + g * 8) = vh;
    *(f16x8*)(Wl + g * 8) = vl;
}

// enc_h (fp32 [16384][512]) -> fragment-ordered split hT images (1048576 granules)
__global__ void hT_init_kernel(const float* __restrict__ src,
                               f16* __restrict__ dh, f16* __restrict__ dl) {
    size_t g = (size_t)blockIdx.x * 256 + threadIdx.x;    // granule id
    int ln = g & 63;  size_t r = g >> 6;                   // r = kk*512 + mb
    int mb = (int)(r & 511); int kk = (int)(r >> 9);
    int m = mb * 32 + (ln & 31);
    int k = kk * 16 + (ln >> 5) * 8;
    const float* s = src + (size_t)m * HDIM + k;
    f16x8 vh, vl;
    #pragma unroll
    for (int i = 0; i < 8; i++) {
        float x = s[i] * SH;
        f16 h = (f16)x;
        vh[i] = h;
        vl[i] = (f16)(x - (float)h);
    }
    *(f16x8*)(dh + g * 8) = vh;
    *(f16x8*)(dl + g * 8) = vl;
}

// ---------------------------------------------------------------------------
// MFMA GEMM (3-pass fp16 split) + fused LSTM cell, fragment-ordered LDS.
// Block: 256 thr = 4 waves; tile 256m x 128n (n = gate*32+jj, gate-major).
// Wave wm owns m-range wm*64 (mt = wm*2, wm*2+1), all 4 gate-tiles.
// mfma_f32_32x32x16_f16: D[row=(reg&3)+8*(reg>>2)+4*(lane>>5)][col=lane&31].
// ---------------------------------------------------------------------------
__global__ __launch_bounds__(256)
void gemm_cell_mfma(const f16* __restrict__ hT_h, const f16* __restrict__ hT_l,
                    f16* __restrict__ hTo_h, f16* __restrict__ hTo_l,
                    float* __restrict__ c,
                    const f16* __restrict__ Wimg_h, const f16* __restrict__ Wimg_l,
                    const float* __restrict__ xb) {
    __shared__ __align__(16) char smem_raw[49152];
    f16* Alds = (f16*)smem_raw;                 // [sp][ks][mt8][512]  32 KB
    f16* Blds = (f16*)(smem_raw + 32768);       // [sp][ks][g4][512]   16 KB
#define AOFF(sp, ks, mt) ((((sp) * 2 + (ks)) * 8 + (mt)) * 512)
#define BOFF(sp, ks, g)  ((((sp) * 2 + (ks)) * 4 + (g)) * 512)

    const int tid  = threadIdx.x;
    const int lane = tid & 63;
    const int wave = tid >> 6;
    const int wm   = wave;            // m quarter for compute
    const int spw  = wave >> 1;       // staging: split this wave loads
    const int ksw  = wave & 1;        // staging: k-sub this wave loads
    const int jb   = blockIdx.y;
    const int mb0  = blockIdx.x * 8;  // first 32-m tile index
    const int m0   = blockIdx.x * 256;
    const int j0   = jb * 32;

    const int half = lane >> 5;
    const int l31  = lane & 31;

    f32x16 acc[2][4];
    #pragma unroll
    for (int t = 0; t < 2; t++)
        #pragma unroll
        for (int g = 0; g < 4; g++)
            #pragma unroll
            for (int r = 0; r < 16; r++) acc[t][g][r] = 0.0f;

    const f16* Asrc = spw ? hT_l : hT_h;
    const f16* Bsrc = spw ? Wimg_l : Wimg_h;
    // running pointers (kc stride: A = 2*512*512 f16, B = 2*4*512 f16)
    const f16* aptr = Asrc + ((size_t)ksw * 512 + mb0) * 512 + lane * 8;
    const f16* bptr = Bsrc + (((size_t)jb * 16 * 2 + ksw) * 4) * 512 + lane * 8;

    for (int kc = 0; kc < 16; kc++) {
        __syncthreads();   // previous tile's fragment reads complete
        #pragma unroll
        for (int mt = 0; mt < 8; mt++)
            gload16(aptr + mt * 512, Alds + AOFF(spw, ksw, mt) + lane * 8);
        #pragma unroll
        for (int g = 0; g < 4; g++)
            gload16(bptr + g * 512, Blds + BOFF(spw, ksw, g) + lane * 8);
        aptr += 2 * 512 * 512;
        bptr += 2 * 4 * 512;
        __syncthreads();   // drain vmcnt -> tile ready

        #pragma unroll
        for (int ks = 0; ks < 2; ks++) {
            f16x8 a_h[2], a_l[2];
            #pragma unroll
            for (int t = 0; t < 2; t++) {
                a_h[t] = *(const f16x8*)(Alds + AOFF(0, ks, wm * 2 + t) + lane * 8);
                a_l[t] = *(const f16x8*)(Alds + AOFF(1, ks, wm * 2 + t) + lane * 8);
            }
            #pragma unroll
            for (int g = 0; g < 4; g++) {
                f16x8 b_h = *(const f16x8*)(Blds + BOFF(0, ks, g) + lane * 8);
                f16x8 b_l = *(const f16x8*)(Blds + BOFF(1, ks, g) + lane * 8);
                #pragma unroll
                for (int t = 0; t < 2; t++) {
                    acc[t][g] = __builtin_amdgcn_mfma_f32_32x32x16_f16(a_h[t], b_h, acc[t][g], 0, 0, 0);
                    acc[t][g] = __builtin_amdgcn_mfma_f32_32x32x16_f16(a_h[t], b_l, acc[t][g], 0, 0, 0);
                    acc[t][g] = __builtin_amdgcn_mfma_f32_32x32x16_f16(a_l[t], b_h, acc[t][g], 0, 0, 0);
                }
            }
        }
    }

    // ---- epilogue: cell update + hT-image production via LDS bounce ----
    __syncthreads();                       // all fragment reads done; reuse smem
    unsigned int* hstage = (unsigned int*)smem_raw;   // [m:256][j:33] packed (hi,lo)

    const float xbi = xb[0 * HDIM + j0 + l31];
    const float xbf = xb[1 * HDIM + j0 + l31];
    const float xbg = xb[2 * HDIM + j0 + l31];
    const float xbo = xb[3 * HDIM + j0 + l31];
    #pragma unroll
    for (int t = 0; t < 2; t++) {
        #pragma unroll
        for (int reg = 0; reg < 16; reg++) {
            int row = (reg & 3) + 8 * (reg >> 2) + 4 * half;
            int ml  = wm * 64 + t * 32 + row;          // local m (0..255)
            float gi = acc[t][0][reg] * SINV + xbi;
            float gf = acc[t][1][reg] * SINV + xbf;
            float gg = acc[t][2][reg] * SINV + xbg;
            float go = acc[t][3][reg] * SINV + xbo;
            float si = 1.0f / (1.0f + expf(-gi));
            float sf = 1.0f / (1.0f + expf(-gf));
            float tg = tanhf(gg);
            float so = 1.0f / (1.0f + expf(-go));
            size_t idx = (size_t)(m0 + ml) * HDIM + j0 + l31;
            float cn = sf * c[idx] + si * tg;
            c[idx] = cn;
            float hs = so * tanhf(cn) * SH;
            f16 hh = (f16)hs;
            f16 hl = (f16)(hs - (float)hh);
            union { f16 h[2]; unsigned int u; } pk;
            pk.h[0] = hh; pk.h[1] = hl;
            hstage[ml * 33 + l31] = pk.u;
        }
    }
    __syncthreads();

    // emit 1024 granules per split: q = (ksp<<9)|(mbl<<6)|ln
    #pragma unroll
    for (int s = 0; s < 4; s++) {
        int q   = tid + s * 256;
        int ksp = q >> 9;
        int mbl = (q >> 6) & 7;
        int ln  = q & 63;
        int mrow = mbl * 32 + (ln & 31);
        int jj8  = ksp * 16 + (ln >> 5) * 8;
        f16x8 vh, vl;
        #pragma unroll
        for (int i = 0; i < 8; i++) {
            union { unsigned int u; f16 h[2]; } pk;
            pk.u = hstage[mrow * 33 + jj8 + i];
            vh[i] = pk.h[0];
            vl[i] = pk.h[1];
        }
        size_t gq = ((size_t)(jb * 2 + ksp) * 512 + mb0 + mbl) * 64 + ln;
        *(f16x8*)(hTo_h + gq * 8) = vh;
        *(f16x8*)(hTo_l + gq * 8) = vl;
    }
#undef AOFF
#undef BOFF
}

// ---------------------------------------------------------------------------
// Per-step output: logits = h @ W_out^T + b_out (V=32), argmax/softmax,
// one-hot message, mask bookkeeping, per-block log-prob partial.
// h comes from the fragment-ordered hT split images.
// ---------------------------------------------------------------------------
__global__ __launch_bounds__(256)
void out_step_kernel(const f16* __restrict__ hTh, const f16* __restrict__ hTl,
                     const float* __restrict__ W_out,
                     const float* __restrict__ b_out,
                     float* __restrict__ mask,
                     float* __restrict__ msg_t,
                     float* __restrict__ maskout_t,
                     float* __restrict__ lp_part,
                     const int* __restrict__ eos_ptr) {
    __shared__ __align__(16) float hs[8][132];
    __shared__ float ws[128][32];
    __shared__ float red[8];

    const int tid = threadIdx.x;
    const int v   = tid & 31;
    const int bb  = tid >> 5;          // 0..7
    const int b0  = blockIdx.x * 8;
    const int eos = *eos_ptr;

    float logit = 0.0f;
    for (int k0 = 0; k0 < HDIM; k0 += 128) {
        __syncthreads();
        if (tid < 128) {   // stage h: 8 rows x 128 k from hT granules
            int bidx = tid & 7, gi = tid >> 3;      // gi 0..15
            int kk   = (k0 >> 4) + (gi >> 1);
            int hf   = gi & 1;
            int b    = b0 + bidx;
            size_t gq = ((size_t)kk * 512 + (b >> 5)) * 64 + hf * 32 + (b & 31);
            f16x8 vh = *(const f16x8*)(hTh + gq * 8);
            f16x8 vl = *(const f16x8*)(hTl + gq * 8);
            int kl = (gi >> 1) * 16 + hf * 8;
            #pragma unroll
            for (int i = 0; i < 8; i++)
                hs[bidx][kl + i] = ((float)vh[i] + (float)vl[i]) * HINV;
        }
        {   // stage W_out transposed
            int kk = bb * 16;
            const float* src = W_out + (size_t)v * HDIM + k0 + kk;
            float4 q0 = *(const float4*)(src + 0);
            float4 q1 = *(const float4*)(src + 4);
            float4 q2 = *(const float4*)(src + 8);
            float4 q3 = *(const float4*)(src + 12);
            ws[kk + 0][v] = q0.x;  ws[kk + 1][v] = q0.y;
            ws[kk + 2][v] = q0.z;  ws[kk + 3][v] = q0.w;
            ws[kk + 4][v] = q1.x;  ws[kk + 5][v] = q1.y;
            ws[kk + 6][v] = q1.z;  ws[kk + 7][v] = q1.w;
            ws[kk + 8][v] = q2.x;  ws[kk + 9][v] = q2.y;
            ws[kk + 10][v] = q2.z; ws[kk + 11][v] = q2.w;
            ws[kk + 12][v] = q3.x; ws[kk + 13][v] = q3.y;
            ws[kk + 14][v] = q3.z; ws[kk + 15][v] = q3.w;
        }
        __syncthreads();
        #pragma unroll
        for (int k = 0; k < 128; k++)
            logit = fmaf(hs[bb][k], ws[k][v], logit);
    }
    logit += b_out[v];

    // argmax over 32 lanes, first-index tie-break (np.argmax semantics)
    float mval = logit;
    int   midx = v;
    #pragma unroll
    for (int off = 16; off > 0; off >>= 1) {
        float ov = __shfl_xor(mval, off, 32);
        int   oi = __shfl_xor(midx, off, 32);
        if (ov > mval || (ov == mval && oi < midx)) { mval = ov; midx = oi; }
    }
    float s = expf(logit - mval);
    #pragma unroll
    for (int off = 16; off > 0; off >>= 1) s += __shfl_xor(s, off, 32);

    const int b = b0 + bb;
    msg_t[(size_t)b * VOCAB + v] = (v == midx) ? 1.0f : 0.0f;
    if (v == 0) {
        float mo = mask[b];
        maskout_t[b] = mo;
        red[bb] = mo * (-logf(s));    // log softmax at argmax = -log(sum)
        if (midx == eos) mask[b] = 0.0f;
    }
    __syncthreads();
    if (tid == 0) {
        float t = 0.0f;
        #pragma unroll
        for (int i = 0; i < 8; i++) t += red[i];
        lp_part[blockIdx.x] = t;
    }
}

__global__ void reduce_lp_kernel(const float* __restrict__ parts, int n,
                                 float* __restrict__ out) {
    __shared__ float sm[256];
    float s = 0.0f;
    for (int i = threadIdx.x; i < n; i += 256) s += parts[i];
    sm[threadIdx.x] = s;
    __syncthreads();
    for (int off = 128; off > 0; off >>= 1) {
        if (threadIdx.x < off) sm[threadIdx.x] += sm[threadIdx.x + off];
        __syncthreads();
    }
    if (threadIdx.x == 0) *out = sm[0];
}

// ---------------------------------------------------------------------------
extern "C" void kernel_launch(void* const* d_in, const int* in_sizes, int n_in,
                              void* d_out, int out_size, void* d_ws, size_t ws_size,
                              hipStream_t stream) {
    const float* enc_h  = (const float*)d_in[0];
    const float* enc_c  = (const float*)d_in[1];
    const float* W_ih   = (const float*)d_in[2];
    const float* b_ih   = (const float*)d_in[3];
    const float* W_hh   = (const float*)d_in[4];
    const float* b_hh   = (const float*)d_in[5];
    const float* W_out  = (const float*)d_in[6];
    const float* b_out  = (const float*)d_in[7];
    const float* x0     = (const float*)d_in[8];
    const int*   eosP   = (const int*)d_in[9];

    float* out     = (float*)d_out;
    float* msg     = out;                                   // [20,16384,32]
    float* maskout = out + (size_t)STEPS * BATCH * VOCAB;   // [20,1,16384]
    float* lp_out  = maskout + (size_t)STEPS * BATCH;       // scalar

    const size_t NH = (size_t)BATCH * HDIM;                 // 8388608
    char* w = (char*)d_ws;
    f16* hTh_a = (f16*)w;            w += NH * sizeof(f16);
    f16* hTl_a = (f16*)w;            w += NH * sizeof(f16);
    f16* hTh_b = (f16*)w;            w += NH * sizeof(f16);
    f16* hTl_b = (f16*)w;            w += NH * sizeof(f16);
    float* cbuf = (float*)w;         w += NH * sizeof(float);
    f16* Wimg_h = (f16*)w;           w += (size_t)G4 * HDIM * sizeof(f16);
    f16* Wimg_l = (f16*)w;           w += (size_t)G4 * HDIM * sizeof(f16);
    float* xb = (float*)w;           w += G4 * sizeof(float);
    float* maskbuf = (float*)w;      w += BATCH * sizeof(float);
    float* lp_parts = (float*)w;     // STEPS * (BATCH/8) floats

    hipMemcpyAsync(cbuf, enc_c, NH * sizeof(float), hipMemcpyDeviceToDevice, stream);
    init_mask_kernel<<<(BATCH + 255) / 256, 256, 0, stream>>>(maskbuf);
    init_xb_kernel<<<(G4 + 255) / 256, 256, 0, stream>>>(W_ih, b_ih, b_hh, x0, xb);
    wimg_kernel<<<(G4 * HDIM / 8) / 256, 256, 0, stream>>>(W_hh, Wimg_h, Wimg_l);
    hT_init_kernel<<<(int)((NH / 8) / 256), 256, 0, stream>>>(enc_h, hTh_a, hTl_a);

    for (int t = 0; t < STEPS; t++) {
        const f16* hi_in = (t & 1) ? hTh_b : hTh_a;
        const f16* lo_in = (t & 1) ? hTl_b : hTl_a;
        f16* hi_out      = (t & 1) ? hTh_a : hTh_b;
        f16* lo_out      = (t & 1) ? hTl_a : hTl_b;
        gemm_cell_mfma<<<dim3(BATCH / 256, HDIM / 32), 256, 0, stream>>>(
            hi_in, lo_in, hi_out, lo_out, cbuf, Wimg_h, Wimg_l, xb);
        out_step_kernel<<<BATCH / 8, 256, 0, stream>>>(
            hi_out, lo_out, W_out, b_out, maskbuf,
            msg + (size_t)t * BATCH * VOCAB,
            maskout + (size_t)t * BATCH,
            lp_parts + (size_t)t * (BATCH / 8),
            eosP);
    }
    reduce_lp_kernel<<<1, 256, 0, stream>>>(lp_parts, STEPS * (BATCH / 8), lp_out);
}

// Round 5
// 3362.370 us; speedup vs baseline: 1.3750x; 1.2774x over previous
//
#include <hip/hip_runtime.h>
#include <math.h>

#define BATCH 16384
#define HDIM  512
#define VOCAB 32
#define STEPS 20
#define G4    2048

typedef _Float16 f16;
typedef _Float16 f16x8 __attribute__((ext_vector_type(8)));
typedef float    f32x16 __attribute__((ext_vector_type(16)));

#define SH   256.0f            // h pre-scale before fp16 split
#define SW   1024.0f           // W pre-scale before fp16 split
#define SINV (1.0f / (SH * SW))
#define HINV (1.0f / SH)

// Fragment-ordered global images (granule = 16 B = 8 f16 = one lane's A/B frag):
//  hT  [kk:32][mb:512][lane:64]          granule(kk,mb,lane) =
//        h[m = mb*32 + (lane&31)][k = kk*16 + (lane>>5)*8 .. +8]
//  Wimg row r = jb*128 + kc*8 + ks*4 + g, granule(r,lane) =
//        W[n = g*512 + jb*32 + (lane&31)][k = kc*32 + ks*16 + (lane>>5)*8 .. +8]

__device__ __forceinline__ void gload16(const void* g, void* l) {
#if defined(__has_builtin) && __has_builtin(__builtin_amdgcn_global_load_lds)
    __builtin_amdgcn_global_load_lds(
        (const __attribute__((address_space(1))) void*)g,
        (__attribute__((address_space(3))) void*)l, 16, 0, 0);
#else
    *(float4*)l = *(const float4*)g;
#endif
}

// ---------------------------------------------------------------------------
// init / prep kernels (once per launch, outside the step loop)
// ---------------------------------------------------------------------------
__global__ void init_xb_kernel(const float* __restrict__ W_ih,
                               const float* __restrict__ b_ih,
                               const float* __restrict__ b_hh,
                               const float* __restrict__ x0,
                               float* __restrict__ xb) {
    int n = blockIdx.x * blockDim.x + threadIdx.x;
    if (n >= G4) return;
    float s = b_ih[n] + b_hh[n];
    const float* wr = W_ih + (size_t)n * VOCAB;
    #pragma unroll
    for (int v = 0; v < VOCAB; v++) s += wr[v] * x0[v];
    xb[n] = s;
}

__global__ void init_mask_kernel(float* __restrict__ mask) {
    int b = blockIdx.x * blockDim.x + threadIdx.x;
    if (b < BATCH) mask[b] = 1.0f;
}

// W_hh (fp32 [2048][512]) -> fragment-ordered split images (131072 granules)
__global__ void wimg_kernel(const float* __restrict__ W_hh,
                            f16* __restrict__ Wh, f16* __restrict__ Wl) {
    size_t g  = (size_t)blockIdx.x * 256 + threadIdx.x;   // granule id
    int ln = g & 63;  size_t r = g >> 6;                   // r = ((jb*16+kc)*2+ks)*4+gg
    int gg = r & 3;   size_t r2 = r >> 2;
    int ks = r2 & 1;  size_t r3 = r2 >> 1;
    int kc = r3 & 15; int jb = (int)(r3 >> 4);
    int n = gg * 512 + jb * 32 + (ln & 31);
    int k = kc * 32 + ks * 16 + (ln >> 5) * 8;
    const float* s = W_hh + (size_t)n * HDIM + k;
    f16x8 vh, vl;
    #pragma unroll
    for (int i = 0; i < 8; i++) {
        float x = s[i] * SW;
        f16 h = (f16)x;
        vh[i] = h;
        vl[i] = (f16)(x - (float)h);
    }
    *(f16x8*)(Wh + g * 8) = vh;
    *(f16x8*)(Wl + g * 8) = vl;
}

// enc_h (fp32 [16384][512]) -> fragment-ordered split hT images (1048576 granules)
__global__ void hT_init_kernel(const float* __restrict__ src,
                               f16* __restrict__ dh, f16* __restrict__ dl) {
    size_t g = (size_t)blockIdx.x * 256 + threadIdx.x;    // granule id
    int ln = g & 63;  size_t r = g >> 6;                   // r = kk*512 + mb
    int mb = (int)(r & 511); int kk = (int)(r >> 9);
    int m = mb * 32 + (ln & 31);
    int k = kk * 16 + (ln >> 5) * 8;
    const float* s = src + (size_t)m * HDIM + k;
    f16x8 vh, vl;
    #pragma unroll
    for (int i = 0; i < 8; i++) {
        float x = s[i] * SH;
        f16 h = (f16)x;
        vh[i] = h;
        vl[i] = (f16)(x - (float)h);
    }
    *(f16x8*)(dh + g * 8) = vh;
    *(f16x8*)(dl + g * 8) = vl;
}

// ---------------------------------------------------------------------------
// MFMA GEMM (3-pass fp16 split) + fused LSTM cell.
// Block: 256 thr = 4 waves; tile 256m x 128n (n = gate*32+jj, gate-major).
// Wave wm owns 64 m (2 mtiles), all 4 gate-tiles.  A: global->reg (hi-split
// prefetched one chunk ahead; lo loaded post-barrier, consumed in pass 3).
// B: LDS double-buffer, global_load_lds; loads cross one full chunk before
// the consuming barrier drains them.
// mfma_f32_32x32x16_f16: D[row=(reg&3)+8*(reg>>2)+4*(lane>>5)][col=lane&31].
// ---------------------------------------------------------------------------
__global__ __launch_bounds__(256, 2)
void gemm_cell_mfma(const f16* __restrict__ hT_h, const f16* __restrict__ hT_l,
                    f16* __restrict__ hTo_h, f16* __restrict__ hTo_l,
                    float* __restrict__ c,
                    const f16* __restrict__ Wimg_h, const f16* __restrict__ Wimg_l,
                    const float* __restrict__ xb) {
    __shared__ __align__(16) char smem_raw[34048];   // 32 KB B dbuf | 33792 B hstage
    f16* Blds = (f16*)smem_raw;   // row = (buf*16 + sp*8 + ks*4 + g), 512 f16/row

    const int tid  = threadIdx.x;
    const int lane = tid & 63;
    const int wave = tid >> 6;
    const int wm   = wave;            // compute: m quarter
    const int spw  = wave >> 1;       // staging: split image
    const int ksw  = wave & 1;        // staging: k-sub
    const int jb   = blockIdx.y;
    const int mb0  = blockIdx.x * 8;
    const int m0   = blockIdx.x * 256;
    const int j0   = jb * 32;
    const int half = lane >> 5;
    const int l31  = lane & 31;

    f32x16 acc[2][4];
    #pragma unroll
    for (int t = 0; t < 2; t++)
        #pragma unroll
        for (int g = 0; g < 4; g++)
            #pragma unroll
            for (int r = 0; r < 16; r++) acc[t][g][r] = 0.0f;

    // B staging: this wave loads 4 gate-rows of its fixed (spw, ksw)
    const f16* bsrc0 = (spw ? Wimg_l : Wimg_h)
                     + ((size_t)jb * 128 + ksw * 4) * 512 + lane * 8;
    f16* bdst0 = Blds + (size_t)(spw * 8 + ksw * 4) * 512 + lane * 8;

    auto stage_b = [&](int kc, int buf) {
        const f16* s = bsrc0 + (size_t)kc * 4096;
        f16* d = bdst0 + buf * 16 * 512;
        #pragma unroll
        for (int g = 0; g < 4; g++)
            gload16(s + g * 512, d + g * 512);
    };

    // A fragments: element offset = ((kk*512) + mb)*512 + lane*8, mb = mb0+wm*2+t
    const size_t abase0 = ((size_t)mb0 + wm * 2) * 512 + lane * 8;
    auto load_ah = [&](int kc, f16x8 (&dst)[2][2]) {
        #pragma unroll
        for (int ks = 0; ks < 2; ks++)
            #pragma unroll
            for (int t = 0; t < 2; t++)
                dst[ks][t] = *(const f16x8*)(hT_h + abase0
                               + (size_t)(kc * 2 + ks) * (512 * 512) + t * 512);
    };
    auto load_al = [&](int kc, f16x8 (&dst)[2][2]) {
        #pragma unroll
        for (int ks = 0; ks < 2; ks++)
            #pragma unroll
            for (int t = 0; t < 2; t++)
                dst[ks][t] = *(const f16x8*)(hT_l + abase0
                               + (size_t)(kc * 2 + ks) * (512 * 512) + t * 512);
    };

    auto compute = [&](f16x8 (&ah)[2][2], f16x8 (&al)[2][2], int buf) {
        #pragma unroll
        for (int ks = 0; ks < 2; ks++) {
            f16x8 bh[4], bl[4];
            #pragma unroll
            for (int g = 0; g < 4; g++) {
                bh[g] = *(const f16x8*)(Blds + (size_t)(buf * 16 + ks * 4 + g) * 512 + lane * 8);
                bl[g] = *(const f16x8*)(Blds + (size_t)(buf * 16 + 8 + ks * 4 + g) * 512 + lane * 8);
            }
            #pragma unroll
            for (int g = 0; g < 4; g++)
                #pragma unroll
                for (int t = 0; t < 2; t++) {
                    acc[t][g] = __builtin_amdgcn_mfma_f32_32x32x16_f16(ah[ks][t], bh[g], acc[t][g], 0, 0, 0);
                    acc[t][g] = __builtin_amdgcn_mfma_f32_32x32x16_f16(ah[ks][t], bl[g], acc[t][g], 0, 0, 0);
                }
            #pragma unroll
            for (int g = 0; g < 4; g++)
                #pragma unroll
                for (int t = 0; t < 2; t++)
                    acc[t][g] = __builtin_amdgcn_mfma_f32_32x32x16_f16(al[ks][t], bh[g], acc[t][g], 0, 0, 0);
        }
    };

    f16x8 ah0[2][2], ah1[2][2], al[2][2];
    stage_b(0, 0);
    load_ah(0, ah0);
    for (int kc2 = 0; kc2 < 8; kc2++) {
        const int kc = kc2 * 2;
        __syncthreads();                 // buf0(kc) + ah0 ready (issued 1 chunk ago)
        stage_b(kc + 1, 1);              // prefetch into buf1
        load_ah(kc + 1, ah1);
        load_al(kc, al);                 // consumed in pass 3 (~500+ cyc away)
        compute(ah0, al, 0);
        __syncthreads();                 // buf1(kc+1) + ah1 ready
        stage_b(kc + 2, 0);              // kc+2==16 on last iter: benign overrun
        load_ah(kc + 2, ah0);            //   (reads stay inside workspace)
        load_al(kc + 1, al);
        compute(ah1, al, 1);
    }

    // ---- epilogue: cell update + hT-image production via LDS bounce ----
    __syncthreads();                     // all B reads done; reuse smem
    unsigned int* hstage = (unsigned int*)smem_raw;   // [m:256][j:33] packed (hi,lo)

    const float xbi = xb[0 * HDIM + j0 + l31];
    const float xbf = xb[1 * HDIM + j0 + l31];
    const float xbg = xb[2 * HDIM + j0 + l31];
    const float xbo = xb[3 * HDIM + j0 + l31];
    #pragma unroll
    for (int t = 0; t < 2; t++) {
        #pragma unroll
        for (int reg = 0; reg < 16; reg++) {
            int row = (reg & 3) + 8 * (reg >> 2) + 4 * half;
            int ml  = wm * 64 + t * 32 + row;          // local m (0..255)
            float gi = acc[t][0][reg] * SINV + xbi;
            float gf = acc[t][1][reg] * SINV + xbf;
            float gg = acc[t][2][reg] * SINV + xbg;
            float go = acc[t][3][reg] * SINV + xbo;
            float si = 1.0f / (1.0f + expf(-gi));
            float sf = 1.0f / (1.0f + expf(-gf));
            float tg = tanhf(gg);
            float so = 1.0f / (1.0f + expf(-go));
            size_t idx = (size_t)(m0 + ml) * HDIM + j0 + l31;
            float cn = sf * c[idx] + si * tg;
            c[idx] = cn;
            float hs = so * tanhf(cn) * SH;
            f16 hh = (f16)hs;
            f16 hl = (f16)(hs - (float)hh);
            union { f16 h[2]; unsigned int u; } pk;
            pk.h[0] = hh; pk.h[1] = hl;
            hstage[ml * 33 + l31] = pk.u;
        }
    }
    __syncthreads();

    // emit 1024 granules per split: q = (ksp<<9)|(mbl<<6)|ln
    #pragma unroll
    for (int s = 0; s < 4; s++) {
        int q   = tid + s * 256;
        int ksp = q >> 9;
        int mbl = (q >> 6) & 7;
        int ln  = q & 63;
        int mrow = mbl * 32 + (ln & 31);
        int jj8  = ksp * 16 + (ln >> 5) * 8;
        f16x8 vh, vl;
        #pragma unroll
        for (int i = 0; i < 8; i++) {
            union { unsigned int u; f16 h[2]; } pk;
            pk.u = hstage[mrow * 33 + jj8 + i];
            vh[i] = pk.h[0];
            vl[i] = pk.h[1];
        }
        size_t gq = ((size_t)(jb * 2 + ksp) * 512 + mb0 + mbl) * 64 + ln;
        *(f16x8*)(hTo_h + gq * 8) = vh;
        *(f16x8*)(hTo_l + gq * 8) = vl;
    }
}

// ---------------------------------------------------------------------------
// Per-step output: logits = h @ W_out^T + b_out (V=32), argmax/softmax,
// one-hot message, mask bookkeeping, per-block log-prob partial.
// ---------------------------------------------------------------------------
__global__ __launch_bounds__(256)
void out_step_kernel(const f16* __restrict__ hTh, const f16* __restrict__ hTl,
                     const float* __restrict__ W_out,
                     const float* __restrict__ b_out,
                     float* __restrict__ mask,
                     float* __restrict__ msg_t,
                     float* __restrict__ maskout_t,
                     float* __restrict__ lp_part,
                     const int* __restrict__ eos_ptr) {
    __shared__ __align__(16) float hs[8][132];
    __shared__ float ws[128][32];
    __shared__ float red[8];

    const int tid = threadIdx.x;
    const int v   = tid & 31;
    const int bb  = tid >> 5;          // 0..7
    const int b0  = blockIdx.x * 8;
    const int eos = *eos_ptr;

    float logit = 0.0f;
    for (int k0 = 0; k0 < HDIM; k0 += 128) {
        __syncthreads();
        if (tid < 128) {   // stage h: 8 rows x 128 k from hT granules
            int bidx = tid & 7, gi = tid >> 3;      // gi 0..15
            int kk   = (k0 >> 4) + (gi >> 1);
            int hf   = gi & 1;
            int b    = b0 + bidx;
            size_t gq = ((size_t)kk * 512 + (b >> 5)) * 64 + hf * 32 + (b & 31);
            f16x8 vh = *(const f16x8*)(hTh + gq * 8);
            f16x8 vl = *(const f16x8*)(hTl + gq * 8);
            int kl = (gi >> 1) * 16 + hf * 8;
            #pragma unroll
            for (int i = 0; i < 8; i++)
                hs[bidx][kl + i] = ((float)vh[i] + (float)vl[i]) * HINV;
        }
        {   // stage W_out transposed
            int kk = bb * 16;
            const float* src = W_out + (size_t)v * HDIM + k0 + kk;
            float4 q0 = *(const float4*)(src + 0);
            float4 q1 = *(const float4*)(src + 4);
            float4 q2 = *(const float4*)(src + 8);
            float4 q3 = *(const float4*)(src + 12);
            ws[kk + 0][v] = q0.x;  ws[kk + 1][v] = q0.y;
            ws[kk + 2][v] = q0.z;  ws[kk + 3][v] = q0.w;
            ws[kk + 4][v] = q1.x;  ws[kk + 5][v] = q1.y;
            ws[kk + 6][v] = q1.z;  ws[kk + 7][v] = q1.w;
            ws[kk + 8][v] = q2.x;  ws[kk + 9][v] = q2.y;
            ws[kk + 10][v] = q2.z; ws[kk + 11][v] = q2.w;
            ws[kk + 12][v] = q3.x; ws[kk + 13][v] = q3.y;
            ws[kk + 14][v] = q3.z; ws[kk + 15][v] = q3.w;
        }
        __syncthreads();
        #pragma unroll
        for (int k = 0; k < 128; k++)
            logit = fmaf(hs[bb][k], ws[k][v], logit);
    }
    logit += b_out[v];

    // argmax over 32 lanes, first-index tie-break (np.argmax semantics)
    float mval = logit;
    int   midx = v;
    #pragma unroll
    for (int off = 16; off > 0; off >>= 1) {
        float ov = __shfl_xor(mval, off, 32);
        int   oi = __shfl_xor(midx, off, 32);
        if (ov > mval || (ov == mval && oi < midx)) { mval = ov; midx = oi; }
    }
    float s = expf(logit - mval);
    #pragma unroll
    for (int off = 16; off > 0; off >>= 1) s += __shfl_xor(s, off, 32);

    const int b = b0 + bb;
    msg_t[(size_t)b * VOCAB + v] = (v == midx) ? 1.0f : 0.0f;
    if (v == 0) {
        float mo = mask[b];
        maskout_t[b] = mo;
        red[bb] = mo * (-logf(s));    // log softmax at argmax = -log(sum)
        if (midx == eos) mask[b] = 0.0f;
    }
    __syncthreads();
    if (tid == 0) {
        float t = 0.0f;
        #pragma unroll
        for (int i = 0; i < 8; i++) t += red[i];
        lp_part[blockIdx.x] = t;
    }
}

__global__ void reduce_lp_kernel(const float* __restrict__ parts, int n,
                                 float* __restrict__ out) {
    __shared__ float sm[256];
    float s = 0.0f;
    for (int i = threadIdx.x; i < n; i += 256) s += parts[i];
    sm[threadIdx.x] = s;
    __syncthreads();
    for (int off = 128; off > 0; off >>= 1) {
        if (threadIdx.x < off) sm[threadIdx.x] += sm[threadIdx.x + off];
        __syncthreads();
    }
    if (threadIdx.x == 0) *out = sm[0];
}

// ---------------------------------------------------------------------------
extern "C" void kernel_launch(void* const* d_in, const int* in_sizes, int n_in,
                              void* d_out, int out_size, void* d_ws, size_t ws_size,
                              hipStream_t stream) {
    const float* enc_h  = (const float*)d_in[0];
    const float* enc_c  = (const float*)d_in[1];
    const float* W_ih   = (const float*)d_in[2];
    const float* b_ih   = (const float*)d_in[3];
    const float* W_hh   = (const float*)d_in[4];
    const float* b_hh   = (const float*)d_in[5];
    const float* W_out  = (const float*)d_in[6];
    const float* b_out  = (const float*)d_in[7];
    const float* x0     = (const float*)d_in[8];
    const int*   eosP   = (const int*)d_in[9];

    float* out     = (float*)d_out;
    float* msg     = out;                                   // [20,16384,32]
    float* maskout = out + (size_t)STEPS * BATCH * VOCAB;   // [20,1,16384]
    float* lp_out  = maskout + (size_t)STEPS * BATCH;       // scalar

    const size_t NH = (size_t)BATCH * HDIM;                 // 8388608
    char* w = (char*)d_ws;
    f16* hTh_a = (f16*)w;            w += NH * sizeof(f16);
    f16* hTl_a = (f16*)w;            w += NH * sizeof(f16);
    f16* hTh_b = (f16*)w;            w += NH * sizeof(f16);
    f16* hTl_b = (f16*)w;            w += NH * sizeof(f16);
    float* cbuf = (float*)w;         w += NH * sizeof(float);
    f16* Wimg_h = (f16*)w;           w += (size_t)G4 * HDIM * sizeof(f16);
    f16* Wimg_l = (f16*)w;           w += (size_t)G4 * HDIM * sizeof(f16);
    float* xb = (float*)w;           w += G4 * sizeof(float);
    float* maskbuf = (float*)w;      w += BATCH * sizeof(float);
    float* lp_parts = (float*)w;     // STEPS * (BATCH/8) floats

    hipMemcpyAsync(cbuf, enc_c, NH * sizeof(float), hipMemcpyDeviceToDevice, stream);
    init_mask_kernel<<<(BATCH + 255) / 256, 256, 0, stream>>>(maskbuf);
    init_xb_kernel<<<(G4 + 255) / 256, 256, 0, stream>>>(W_ih, b_ih, b_hh, x0, xb);
    wimg_kernel<<<(G4 * HDIM / 8) / 256, 256, 0, stream>>>(W_hh, Wimg_h, Wimg_l);
    hT_init_kernel<<<(int)((NH / 8) / 256), 256, 0, stream>>>(enc_h, hTh_a, hTl_a);

    for (int t = 0; t < STEPS; t++) {
        const f16* hi_in = (t & 1) ? hTh_b : hTh_a;
        const f16* lo_in = (t & 1) ? hTl_b : hTl_a;
        f16* hi_out      = (t & 1) ? hTh_a : hTh_b;
        f16* lo_out      = (t & 1) ? hTl_a : hTl_b;
        gemm_cell_mfma<<<dim3(BATCH / 256, HDIM / 32), 256, 0, stream>>>(
            hi_in, lo_in, hi_out, lo_out, cbuf, Wimg_h, Wimg_l, xb);
        out_step_kernel<<<BATCH / 8, 256, 0, stream>>>(
            hi_out, lo_out, W_out, b_out, maskbuf,
            msg + (size_t)t * BATCH * VOCAB,
            maskout + (size_t)t * BATCH,
            lp_parts + (size_t)t * (BATCH / 8),
            eosP);
    }
    reduce_lp_kernel<<<1, 256, 0, stream>>>(lp_parts, STEPS * (BATCH / 8), lp_out);
}

// Round 6
// 2640.762 us; speedup vs baseline: 1.7507x; 1.2733x over previous
//
#include <hip/hip_runtime.h>
#include <math.h>

#define BATCH 16384
#define HDIM  512
#define VOCAB 32
#define STEPS 20
#define G4    2048

typedef _Float16 f16;
typedef _Float16 f16x8 __attribute__((ext_vector_type(8)));
typedef float    f32x16 __attribute__((ext_vector_type(16)));

#define SH   256.0f            // h pre-scale before fp16 split
#define SW   1024.0f           // W pre-scale before fp16 split
#define SINV (1.0f / (SH * SW))

// Fragment-ordered global images (granule = 16 B = 8 f16 = one lane's A/B frag):
//  hT  [kk:32][mb:512][lane:64]          granule(kk,mb,lane) =
//        h[m = mb*32 + (lane&31)][k = kk*16 + (lane>>5)*8 .. +8]
//  Wimg row r = jb*128 + kc*8 + ks*4 + g, granule(r,lane) =
//        W[n = g*512 + jb*32 + (lane&31)][k = kc*32 + ks*16 + (lane>>5)*8 .. +8]
//  Wout row r = kc*2 + ks (32 rows), granule(r,lane) =
//        W_out[v = lane&31][k = kc*32 + ks*16 + (lane>>5)*8 .. +8]

__device__ __forceinline__ void gload16(const void* g, void* l) {
#if defined(__has_builtin) && __has_builtin(__builtin_amdgcn_global_load_lds)
    __builtin_amdgcn_global_load_lds(
        (const __attribute__((address_space(1))) void*)g,
        (__attribute__((address_space(3))) void*)l, 16, 0, 0);
#else
    *(float4*)l = *(const float4*)g;
#endif
}

__device__ __forceinline__ float fsig(float x)  { return 1.0f / (1.0f + __expf(-x)); }
__device__ __forceinline__ float ftanh(float x) { return 1.0f - 2.0f / (__expf(2.0f * x) + 1.0f); }

// ---------------------------------------------------------------------------
// init / prep kernels (once per launch, outside the step loop)
// ---------------------------------------------------------------------------
__global__ void init_xb_kernel(const float* __restrict__ W_ih,
                               const float* __restrict__ b_ih,
                               const float* __restrict__ b_hh,
                               const float* __restrict__ x0,
                               float* __restrict__ xb) {
    int n = blockIdx.x * blockDim.x + threadIdx.x;
    if (n >= G4) return;
    float s = b_ih[n] + b_hh[n];
    const float* wr = W_ih + (size_t)n * VOCAB;
    #pragma unroll
    for (int v = 0; v < VOCAB; v++) s += wr[v] * x0[v];
    xb[n] = s;
}

__global__ void init_mask_kernel(float* __restrict__ mask) {
    int b = blockIdx.x * blockDim.x + threadIdx.x;
    if (b < BATCH) mask[b] = 1.0f;
}

// W_hh (fp32 [2048][512]) -> fragment-ordered split images (131072 granules)
__global__ void wimg_kernel(const float* __restrict__ W_hh,
                            f16* __restrict__ Wh, f16* __restrict__ Wl) {
    size_t g  = (size_t)blockIdx.x * 256 + threadIdx.x;   // granule id
    int ln = g & 63;  size_t r = g >> 6;                   // r = ((jb*16+kc)*2+ks)*4+gg
    int gg = r & 3;   size_t r2 = r >> 2;
    int ks = r2 & 1;  size_t r3 = r2 >> 1;
    int kc = r3 & 15; int jb = (int)(r3 >> 4);
    int n = gg * 512 + jb * 32 + (ln & 31);
    int k = kc * 32 + ks * 16 + (ln >> 5) * 8;
    const float* s = W_hh + (size_t)n * HDIM + k;
    f16x8 vh, vl;
    #pragma unroll
    for (int i = 0; i < 8; i++) {
        float x = s[i] * SW;
        f16 h = (f16)x;
        vh[i] = h;
        vl[i] = (f16)(x - (float)h);
    }
    *(f16x8*)(Wh + g * 8) = vh;
    *(f16x8*)(Wl + g * 8) = vl;
}

// W_out (fp32 [32][512]) -> fragment-ordered split images (2048 granules)
__global__ void woutimg_kernel(const float* __restrict__ W_out,
                               f16* __restrict__ Oh, f16* __restrict__ Ol) {
    int g  = blockIdx.x * 256 + threadIdx.x;   // 0..2047
    int ln = g & 63;
    int r  = g >> 6;                            // 0..31 = kc*2 + ks
    int kc = r >> 1, ks = r & 1;
    int v  = ln & 31;
    int k  = kc * 32 + ks * 16 + (ln >> 5) * 8;
    const float* s = W_out + (size_t)v * HDIM + k;
    f16x8 vh, vl;
    #pragma unroll
    for (int i = 0; i < 8; i++) {
        float x = s[i] * SW;
        f16 h = (f16)x;
        vh[i] = h;
        vl[i] = (f16)(x - (float)h);
    }
    *(f16x8*)(Oh + (size_t)g * 8) = vh;
    *(f16x8*)(Ol + (size_t)g * 8) = vl;
}

// enc_h (fp32 [16384][512]) -> fragment-ordered split hT images (1048576 granules)
__global__ void hT_init_kernel(const float* __restrict__ src,
                               f16* __restrict__ dh, f16* __restrict__ dl) {
    size_t g = (size_t)blockIdx.x * 256 + threadIdx.x;    // granule id
    int ln = g & 63;  size_t r = g >> 6;                   // r = kk*512 + mb
    int mb = (int)(r & 511); int kk = (int)(r >> 9);
    int m = mb * 32 + (ln & 31);
    int k = kk * 16 + (ln >> 5) * 8;
    const float* s = src + (size_t)m * HDIM + k;
    f16x8 vh, vl;
    #pragma unroll
    for (int i = 0; i < 8; i++) {
        float x = s[i] * SH;
        f16 h = (f16)x;
        vh[i] = h;
        vl[i] = (f16)(x - (float)h);
    }
    *(f16x8*)(dh + g * 8) = vh;
    *(f16x8*)(dl + g * 8) = vl;
}

// ---------------------------------------------------------------------------
// MFMA GEMM (3-pass fp16 split) + fused LSTM cell.  (unchanged structure from
// R5 except __expf-based activations.)
// ---------------------------------------------------------------------------
__global__ __launch_bounds__(256, 2)
void gemm_cell_mfma(const f16* __restrict__ hT_h, const f16* __restrict__ hT_l,
                    f16* __restrict__ hTo_h, f16* __restrict__ hTo_l,
                    float* __restrict__ c,
                    const f16* __restrict__ Wimg_h, const f16* __restrict__ Wimg_l,
                    const float* __restrict__ xb) {
    __shared__ __align__(16) char smem_raw[34048];   // 32 KB B dbuf | 33792 B hstage
    f16* Blds = (f16*)smem_raw;   // row = (buf*16 + sp*8 + ks*4 + g), 512 f16/row

    const int tid  = threadIdx.x;
    const int lane = tid & 63;
    const int wave = tid >> 6;
    const int wm   = wave;            // compute: m quarter
    const int spw  = wave >> 1;       // staging: split image
    const int ksw  = wave & 1;        // staging: k-sub
    const int jb   = blockIdx.y;
    const int mb0  = blockIdx.x * 8;
    const int m0   = blockIdx.x * 256;
    const int j0   = jb * 32;
    const int half = lane >> 5;
    const int l31  = lane & 31;

    f32x16 acc[2][4];
    #pragma unroll
    for (int t = 0; t < 2; t++)
        #pragma unroll
        for (int g = 0; g < 4; g++)
            #pragma unroll
            for (int r = 0; r < 16; r++) acc[t][g][r] = 0.0f;

    const f16* bsrc0 = (spw ? Wimg_l : Wimg_h)
                     + ((size_t)jb * 128 + ksw * 4) * 512 + lane * 8;
    f16* bdst0 = Blds + (size_t)(spw * 8 + ksw * 4) * 512 + lane * 8;

    auto stage_b = [&](int kc, int buf) {
        const f16* s = bsrc0 + (size_t)kc * 4096;
        f16* d = bdst0 + buf * 16 * 512;
        #pragma unroll
        for (int g = 0; g < 4; g++)
            gload16(s + g * 512, d + g * 512);
    };

    const size_t abase0 = ((size_t)mb0 + wm * 2) * 512 + lane * 8;
    auto load_ah = [&](int kc, f16x8 (&dst)[2][2]) {
        #pragma unroll
        for (int ks = 0; ks < 2; ks++)
            #pragma unroll
            for (int t = 0; t < 2; t++)
                dst[ks][t] = *(const f16x8*)(hT_h + abase0
                               + (size_t)(kc * 2 + ks) * (512 * 512) + t * 512);
    };
    auto load_al = [&](int kc, f16x8 (&dst)[2][2]) {
        #pragma unroll
        for (int ks = 0; ks < 2; ks++)
            #pragma unroll
            for (int t = 0; t < 2; t++)
                dst[ks][t] = *(const f16x8*)(hT_l + abase0
                               + (size_t)(kc * 2 + ks) * (512 * 512) + t * 512);
    };

    auto compute = [&](f16x8 (&ah)[2][2], f16x8 (&al)[2][2], int buf) {
        #pragma unroll
        for (int ks = 0; ks < 2; ks++) {
            f16x8 bh[4], bl[4];
            #pragma unroll
            for (int g = 0; g < 4; g++) {
                bh[g] = *(const f16x8*)(Blds + (size_t)(buf * 16 + ks * 4 + g) * 512 + lane * 8);
                bl[g] = *(const f16x8*)(Blds + (size_t)(buf * 16 + 8 + ks * 4 + g) * 512 + lane * 8);
            }
            #pragma unroll
            for (int g = 0; g < 4; g++)
                #pragma unroll
                for (int t = 0; t < 2; t++) {
                    acc[t][g] = __builtin_amdgcn_mfma_f32_32x32x16_f16(ah[ks][t], bh[g], acc[t][g], 0, 0, 0);
                    acc[t][g] = __builtin_amdgcn_mfma_f32_32x32x16_f16(ah[ks][t], bl[g], acc[t][g], 0, 0, 0);
                }
            #pragma unroll
            for (int g = 0; g < 4; g++)
                #pragma unroll
                for (int t = 0; t < 2; t++)
                    acc[t][g] = __builtin_amdgcn_mfma_f32_32x32x16_f16(al[ks][t], bh[g], acc[t][g], 0, 0, 0);
        }
    };

    f16x8 ah0[2][2], ah1[2][2], al[2][2];
    stage_b(0, 0);
    load_ah(0, ah0);
    for (int kc2 = 0; kc2 < 8; kc2++) {
        const int kc = kc2 * 2;
        __syncthreads();                 // buf0(kc) + ah0 ready (issued 1 chunk ago)
        stage_b(kc + 1, 1);
        load_ah(kc + 1, ah1);
        load_al(kc, al);
        compute(ah0, al, 0);
        __syncthreads();                 // buf1(kc+1) + ah1 ready
        stage_b(kc + 2, 0);              // kc+2==16 on last iter: benign overrun
        load_ah(kc + 2, ah0);
        load_al(kc + 1, al);
        compute(ah1, al, 1);
    }

    // ---- epilogue: cell update + hT-image production via LDS bounce ----
    __syncthreads();
    unsigned int* hstage = (unsigned int*)smem_raw;   // [m:256][j:33] packed (hi,lo)

    const float xbi = xb[0 * HDIM + j0 + l31];
    const float xbf = xb[1 * HDIM + j0 + l31];
    const float xbg = xb[2 * HDIM + j0 + l31];
    const float xbo = xb[3 * HDIM + j0 + l31];
    #pragma unroll
    for (int t = 0; t < 2; t++) {
        #pragma unroll
        for (int reg = 0; reg < 16; reg++) {
            int row = (reg & 3) + 8 * (reg >> 2) + 4 * half;
            int ml  = wm * 64 + t * 32 + row;
            float gi = acc[t][0][reg] * SINV + xbi;
            float gf = acc[t][1][reg] * SINV + xbf;
            float gg = acc[t][2][reg] * SINV + xbg;
            float go = acc[t][3][reg] * SINV + xbo;
            float si = fsig(gi);
            float sf = fsig(gf);
            float tg = ftanh(gg);
            float so = fsig(go);
            size_t idx = (size_t)(m0 + ml) * HDIM + j0 + l31;
            float cn = sf * c[idx] + si * tg;
            c[idx] = cn;
            float hs = so * ftanh(cn) * SH;
            f16 hh = (f16)hs;
            f16 hl = (f16)(hs - (float)hh);
            union { f16 h[2]; unsigned int u; } pk;
            pk.h[0] = hh; pk.h[1] = hl;
            hstage[ml * 33 + l31] = pk.u;
        }
    }
    __syncthreads();

    #pragma unroll
    for (int s = 0; s < 4; s++) {
        int q   = tid + s * 256;
        int ksp = q >> 9;
        int mbl = (q >> 6) & 7;
        int ln  = q & 63;
        int mrow = mbl * 32 + (ln & 31);
        int jj8  = ksp * 16 + (ln >> 5) * 8;
        f16x8 vh, vl;
        #pragma unroll
        for (int i = 0; i < 8; i++) {
            union { unsigned int u; f16 h[2]; } pk;
            pk.u = hstage[mrow * 33 + jj8 + i];
            vh[i] = pk.h[0];
            vl[i] = pk.h[1];
        }
        size_t gq = ((size_t)(jb * 2 + ksp) * 512 + mb0 + mbl) * 64 + ln;
        *(f16x8*)(hTo_h + gq * 8) = vh;
        *(f16x8*)(hTo_l + gq * 8) = vl;
    }
}

// ---------------------------------------------------------------------------
// Output step, MFMA edition.  One wave (64 thr) per 32 batch rows; no LDS, no
// barriers.  logits = h @ W_out^T via 3-pass split, A/B frags register-loaded
// from fragment-ordered images (B = 64 KB Wout image, L2-resident broadcast).
// C-layout: D[row=(reg&3)+8*(reg>>2)+4*half][v=lane&31] -> per-reg shuffle
// argmax/softmax across the 32-lane half-group.
// ---------------------------------------------------------------------------
__global__ __launch_bounds__(64)
void out_mfma(const f16* __restrict__ hTh, const f16* __restrict__ hTl,
              const f16* __restrict__ Oh, const f16* __restrict__ Ol,
              const float* __restrict__ b_out,
              float* __restrict__ mask,
              float* __restrict__ msg_t,
              float* __restrict__ maskout_t,
              float* __restrict__ lp_part,
              const int* __restrict__ eos_ptr) {
    const int lane = threadIdx.x;
    const int mb   = blockIdx.x;          // 32-row tile id (0..511)
    const int half = lane >> 5;
    const int l31  = lane & 31;

    f32x16 acc;
    #pragma unroll
    for (int r = 0; r < 16; r++) acc[r] = 0.0f;

    // frag loaders (kc may overrun by <=2: reads land in the adjacent split
    // image inside the workspace -- benign)
    f16x8 ah[3][2], al[3][2], bh[3][2], bl[3][2];
    auto load_frags = [&](int kc, int buf) {
        #pragma unroll
        for (int ks = 0; ks < 2; ks++) {
            size_t ga = ((size_t)(kc * 2 + ks) * 512 + mb) * 64 + lane;
            size_t gb = ((size_t)(kc * 2 + ks)) * 64 + lane;
            ah[buf][ks] = *(const f16x8*)(hTh + ga * 8);
            al[buf][ks] = *(const f16x8*)(hTl + ga * 8);
            bh[buf][ks] = *(const f16x8*)(Oh + gb * 8);
            bl[buf][ks] = *(const f16x8*)(Ol + gb * 8);
        }
    };

    load_frags(0, 0);
    load_frags(1, 1);
    for (int kc = 0; kc < 16; kc++) {
        load_frags(kc + 2, (kc + 2) % 3);
        int b = kc % 3;
        #pragma unroll
        for (int ks = 0; ks < 2; ks++) {
            acc = __builtin_amdgcn_mfma_f32_32x32x16_f16(ah[b][ks], bh[b][ks], acc, 0, 0, 0);
            acc = __builtin_amdgcn_mfma_f32_32x32x16_f16(ah[b][ks], bl[b][ks], acc, 0, 0, 0);
            acc = __builtin_amdgcn_mfma_f32_32x32x16_f16(al[b][ks], bh[b][ks], acc, 0, 0, 0);
        }
    }

    const float bo  = b_out[l31];
    const int   eos = *eos_ptr;
    const int   m0  = mb * 32;
    float lpacc = 0.0f;

    #pragma unroll
    for (int reg = 0; reg < 16; reg++) {
        int row = (reg & 3) + 8 * (reg >> 2) + 4 * half;
        int m   = m0 + row;
        float logit = acc[reg] * SINV + bo;

        float mval = logit;
        int   midx = l31;
        #pragma unroll
        for (int off = 16; off > 0; off >>= 1) {
            float ov = __shfl_xor(mval, off, 32);
            int   oi = __shfl_xor(midx, off, 32);
            if (ov > mval || (ov == mval && oi < midx)) { mval = ov; midx = oi; }
        }
        float s = __expf(logit - mval);
        #pragma unroll
        for (int off = 16; off > 0; off >>= 1) s += __shfl_xor(s, off, 32);

        msg_t[(size_t)m * VOCAB + l31] = (l31 == midx) ? 1.0f : 0.0f;
        if (l31 == 0) {
            float mo = mask[m];
            maskout_t[m] = mo;
            lpacc += mo * (-__logf(s));
            if (midx == eos) mask[m] = 0.0f;
        }
    }
    // fold lane 32's partial into lane 0 (all other lanes carry 0)
    lpacc += __shfl_xor(lpacc, 32);
    if (lane == 0) lp_part[mb] = lpacc;
}

__global__ void reduce_lp_kernel(const float* __restrict__ parts, int n,
                                 float* __restrict__ out) {
    __shared__ float sm[256];
    float s = 0.0f;
    for (int i = threadIdx.x; i < n; i += 256) s += parts[i];
    sm[threadIdx.x] = s;
    __syncthreads();
    for (int off = 128; off > 0; off >>= 1) {
        if (threadIdx.x < off) sm[threadIdx.x] += sm[threadIdx.x + off];
        __syncthreads();
    }
    if (threadIdx.x == 0) *out = sm[0];
}

// ---------------------------------------------------------------------------
extern "C" void kernel_launch(void* const* d_in, const int* in_sizes, int n_in,
                              void* d_out, int out_size, void* d_ws, size_t ws_size,
                              hipStream_t stream) {
    const float* enc_h  = (const float*)d_in[0];
    const float* enc_c  = (const float*)d_in[1];
    const float* W_ih   = (const float*)d_in[2];
    const float* b_ih   = (const float*)d_in[3];
    const float* W_hh   = (const float*)d_in[4];
    const float* b_hh   = (const float*)d_in[5];
    const float* W_out  = (const float*)d_in[6];
    const float* b_out  = (const float*)d_in[7];
    const float* x0     = (const float*)d_in[8];
    const int*   eosP   = (const int*)d_in[9];

    float* out     = (float*)d_out;
    float* msg     = out;                                   // [20,16384,32]
    float* maskout = out + (size_t)STEPS * BATCH * VOCAB;   // [20,1,16384]
    float* lp_out  = maskout + (size_t)STEPS * BATCH;       // scalar

    const size_t NH = (size_t)BATCH * HDIM;                 // 8388608
    char* w = (char*)d_ws;
    f16* hTh_a = (f16*)w;            w += NH * sizeof(f16);
    f16* hTl_a = (f16*)w;            w += NH * sizeof(f16);
    f16* hTh_b = (f16*)w;            w += NH * sizeof(f16);
    f16* hTl_b = (f16*)w;            w += NH * sizeof(f16);
    float* cbuf = (float*)w;         w += NH * sizeof(float);
    f16* Wimg_h = (f16*)w;           w += (size_t)G4 * HDIM * sizeof(f16);
    f16* Wimg_l = (f16*)w;           w += (size_t)G4 * HDIM * sizeof(f16);
    f16* Wout_h = (f16*)w;           w += (size_t)VOCAB * HDIM * sizeof(f16);
    f16* Wout_l = (f16*)w;           w += (size_t)VOCAB * HDIM * sizeof(f16);
    float* xb = (float*)w;           w += G4 * sizeof(float);
    float* maskbuf = (float*)w;      w += BATCH * sizeof(float);
    float* lp_parts = (float*)w;     // STEPS * 512 floats

    hipMemcpyAsync(cbuf, enc_c, NH * sizeof(float), hipMemcpyDeviceToDevice, stream);
    init_mask_kernel<<<(BATCH + 255) / 256, 256, 0, stream>>>(maskbuf);
    init_xb_kernel<<<(G4 + 255) / 256, 256, 0, stream>>>(W_ih, b_ih, b_hh, x0, xb);
    wimg_kernel<<<(G4 * HDIM / 8) / 256, 256, 0, stream>>>(W_hh, Wimg_h, Wimg_l);
    woutimg_kernel<<<8, 256, 0, stream>>>(W_out, Wout_h, Wout_l);
    hT_init_kernel<<<(int)((NH / 8) / 256), 256, 0, stream>>>(enc_h, hTh_a, hTl_a);

    for (int t = 0; t < STEPS; t++) {
        const f16* hi_in = (t & 1) ? hTh_b : hTh_a;
        const f16* lo_in = (t & 1) ? hTl_b : hTl_a;
        f16* hi_out      = (t & 1) ? hTh_a : hTh_b;
        f16* lo_out      = (t & 1) ? hTl_a : hTl_b;
        gemm_cell_mfma<<<dim3(BATCH / 256, HDIM / 32), 256, 0, stream>>>(
            hi_in, lo_in, hi_out, lo_out, cbuf, Wimg_h, Wimg_l, xb);
        out_mfma<<<BATCH / 32, 64, 0, stream>>>(
            hi_out, lo_out, Wout_h, Wout_l, b_out, maskbuf,
            msg + (size_t)t * BATCH * VOCAB,
            maskout + (size_t)t * BATCH,
            lp_parts + (size_t)t * (BATCH / 32),
            eosP);
    }
    reduce_lp_kernel<<<1, 256, 0, stream>>>(lp_parts, STEPS * (BATCH / 32), lp_out);
}

// Round 7
// 2570.427 us; speedup vs baseline: 1.7986x; 1.0274x over previous
//
#include <hip/hip_runtime.h>
#include <math.h>

#define BATCH 16384
#define HDIM  512
#define VOCAB 32
#define STEPS 20
#define G4    2048

typedef _Float16 f16;
typedef _Float16 f16x8 __attribute__((ext_vector_type(8)));
typedef float    f32x16 __attribute__((ext_vector_type(16)));

#define SH   256.0f            // h pre-scale before fp16 split
#define SW   1024.0f           // W pre-scale before fp16 split
#define SINV (1.0f / (SH * SW))

// Fragment-ordered global images (granule = 16 B = 8 f16 = one lane's A/B frag):
//  hT  [kk:32][mb:512][lane:64]          granule(kk,mb,lane) =
//        h[m = mb*32 + (lane&31)][k = kk*16 + (lane>>5)*8 .. +8]
//  Wimg row r = jb*128 + kc*8 + ks*4 + g, granule(r,lane) =
//        W[n = g*512 + jb*32 + (lane&31)][k = kc*32 + ks*16 + (lane>>5)*8 .. +8]
//  Wout row r = kc*2 + ks (32 rows), granule(r,lane) =
//        W_out[v = lane&31][k = kc*32 + ks*16 + (lane>>5)*8 .. +8]

__device__ __forceinline__ void gload16(const void* g, void* l) {
#if defined(__has_builtin) && __has_builtin(__builtin_amdgcn_global_load_lds)
    __builtin_amdgcn_global_load_lds(
        (const __attribute__((address_space(1))) void*)g,
        (__attribute__((address_space(3))) void*)l, 16, 0, 0);
#else
    *(float4*)l = *(const float4*)g;
#endif
}

__device__ __forceinline__ float fsig(float x)  { return 1.0f / (1.0f + __expf(-x)); }
__device__ __forceinline__ float ftanh(float x) { return 1.0f - 2.0f / (__expf(2.0f * x) + 1.0f); }

// ---------------------------------------------------------------------------
// init / prep kernels (once per launch, outside the step loop)
// ---------------------------------------------------------------------------
__global__ void init_xb_kernel(const float* __restrict__ W_ih,
                               const float* __restrict__ b_ih,
                               const float* __restrict__ b_hh,
                               const float* __restrict__ x0,
                               float* __restrict__ xb) {
    int n = blockIdx.x * blockDim.x + threadIdx.x;
    if (n >= G4) return;
    float s = b_ih[n] + b_hh[n];
    const float* wr = W_ih + (size_t)n * VOCAB;
    #pragma unroll
    for (int v = 0; v < VOCAB; v++) s += wr[v] * x0[v];
    xb[n] = s;
}

__global__ void init_mask_kernel(float* __restrict__ mask) {
    int b = blockIdx.x * blockDim.x + threadIdx.x;
    if (b < BATCH) mask[b] = 1.0f;
}

// W_hh (fp32 [2048][512]) -> fragment-ordered split images (131072 granules)
__global__ void wimg_kernel(const float* __restrict__ W_hh,
                            f16* __restrict__ Wh, f16* __restrict__ Wl) {
    size_t g  = (size_t)blockIdx.x * 256 + threadIdx.x;   // granule id
    int ln = g & 63;  size_t r = g >> 6;                   // r = ((jb*16+kc)*2+ks)*4+gg
    int gg = r & 3;   size_t r2 = r >> 2;
    int ks = r2 & 1;  size_t r3 = r2 >> 1;
    int kc = r3 & 15; int jb = (int)(r3 >> 4);
    int n = gg * 512 + jb * 32 + (ln & 31);
    int k = kc * 32 + ks * 16 + (ln >> 5) * 8;
    const float* s = W_hh + (size_t)n * HDIM + k;
    f16x8 vh, vl;
    #pragma unroll
    for (int i = 0; i < 8; i++) {
        float x = s[i] * SW;
        f16 h = (f16)x;
        vh[i] = h;
        vl[i] = (f16)(x - (float)h);
    }
    *(f16x8*)(Wh + g * 8) = vh;
    *(f16x8*)(Wl + g * 8) = vl;
}

// W_out (fp32 [32][512]) -> fragment-ordered split images (2048 granules)
__global__ void woutimg_kernel(const float* __restrict__ W_out,
                               f16* __restrict__ Oh, f16* __restrict__ Ol) {
    int g  = blockIdx.x * 256 + threadIdx.x;   // 0..2047
    int ln = g & 63;
    int r  = g >> 6;                            // 0..31 = kc*2 + ks
    int kc = r >> 1, ks = r & 1;
    int v  = ln & 31;
    int k  = kc * 32 + ks * 16 + (ln >> 5) * 8;
    const float* s = W_out + (size_t)v * HDIM + k;
    f16x8 vh, vl;
    #pragma unroll
    for (int i = 0; i < 8; i++) {
        float x = s[i] * SW;
        f16 h = (f16)x;
        vh[i] = h;
        vl[i] = (f16)(x - (float)h);
    }
    *(f16x8*)(Oh + (size_t)g * 8) = vh;
    *(f16x8*)(Ol + (size_t)g * 8) = vl;
}

// enc_h (fp32 [16384][512]) -> fragment-ordered split hT images (1048576 granules)
__global__ void hT_init_kernel(const float* __restrict__ src,
                               f16* __restrict__ dh, f16* __restrict__ dl) {
    size_t g = (size_t)blockIdx.x * 256 + threadIdx.x;    // granule id
    int ln = g & 63;  size_t r = g >> 6;                   // r = kk*512 + mb
    int mb = (int)(r & 511); int kk = (int)(r >> 9);
    int m = mb * 32 + (ln & 31);
    int k = kk * 16 + (ln >> 5) * 8;
    const float* s = src + (size_t)m * HDIM + k;
    f16x8 vh, vl;
    #pragma unroll
    for (int i = 0; i < 8; i++) {
        float x = s[i] * SH;
        f16 h = (f16)x;
        vh[i] = h;
        vl[i] = (f16)(x - (float)h);
    }
    *(f16x8*)(dh + g * 8) = vh;
    *(f16x8*)(dl + g * 8) = vl;
}

// ---------------------------------------------------------------------------
// Output-step body: one wave computes logits/argmax/softmax for 32 batch rows.
// No LDS, no barriers.  logits = h @ W_out^T via 3-pass split, frags register-
// loaded from fragment-ordered images (Wout image is 128 KB, L2-resident).
// ---------------------------------------------------------------------------
__device__ __forceinline__ void out_body(int lane, int mb,
        const f16* __restrict__ hTh, const f16* __restrict__ hTl,
        const f16* __restrict__ Oh,  const f16* __restrict__ Ol,
        const float* __restrict__ b_out,
        float* __restrict__ mask, float* __restrict__ msg_t,
        float* __restrict__ maskout_t, float* __restrict__ lp_part, int eos) {
    const int half = lane >> 5;
    const int l31  = lane & 31;

    f32x16 acc;
    #pragma unroll
    for (int r = 0; r < 16; r++) acc[r] = 0.0f;

    f16x8 ah[3][2], al[3][2], bh[3][2], bl[3][2];
    auto load_frags = [&](int kc, int buf) {
        #pragma unroll
        for (int ks = 0; ks < 2; ks++) {
            size_t ga = ((size_t)(kc * 2 + ks) * 512 + mb) * 64 + lane;
            size_t gb = ((size_t)(kc * 2 + ks)) * 64 + lane;
            ah[buf][ks] = *(const f16x8*)(hTh + ga * 8);
            al[buf][ks] = *(const f16x8*)(hTl + ga * 8);
            bh[buf][ks] = *(const f16x8*)(Oh + gb * 8);
            bl[buf][ks] = *(const f16x8*)(Ol + gb * 8);
        }
    };

    load_frags(0, 0);
    load_frags(1, 1);
    for (int kc = 0; kc < 16; kc++) {
        if (kc < 14) load_frags(kc + 2, (kc + 2) % 3);
        int b = kc % 3;
        #pragma unroll
        for (int ks = 0; ks < 2; ks++) {
            acc = __builtin_amdgcn_mfma_f32_32x32x16_f16(ah[b][ks], bh[b][ks], acc, 0, 0, 0);
            acc = __builtin_amdgcn_mfma_f32_32x32x16_f16(ah[b][ks], bl[b][ks], acc, 0, 0, 0);
            acc = __builtin_amdgcn_mfma_f32_32x32x16_f16(al[b][ks], bh[b][ks], acc, 0, 0, 0);
        }
    }

    const float bo = b_out[l31];
    const int   m0 = mb * 32;
    float lpacc = 0.0f;

    #pragma unroll
    for (int reg = 0; reg < 16; reg++) {
        int row = (reg & 3) + 8 * (reg >> 2) + 4 * half;
        int m   = m0 + row;
        float logit = acc[reg] * SINV + bo;

        float mval = logit;
        int   midx = l31;
        #pragma unroll
        for (int off = 16; off > 0; off >>= 1) {
            float ov = __shfl_xor(mval, off, 32);
            int   oi = __shfl_xor(midx, off, 32);
            if (ov > mval || (ov == mval && oi < midx)) { mval = ov; midx = oi; }
        }
        float s = __expf(logit - mval);
        #pragma unroll
        for (int off = 16; off > 0; off >>= 1) s += __shfl_xor(s, off, 32);

        msg_t[(size_t)m * VOCAB + l31] = (l31 == midx) ? 1.0f : 0.0f;
        if (l31 == 0) {
            float mo = mask[m];
            maskout_t[m] = mo;
            lpacc += mo * (-__logf(s));
            if (midx == eos) mask[m] = 0.0f;
        }
    }
    lpacc += __shfl_xor(lpacc, 32);   // fold lane 32's partial into lane 0
    if (lane == 0) lp_part[mb] = lpacc;
}

// ---------------------------------------------------------------------------
// Fused step kernel.  Blocks 0..1023: MFMA GEMM (gates = h(t-1) @ W_hh^T,
// 3-pass fp16 split) + LSTM cell -> h(t) images.  Blocks 1024..1151 (4 waves
// each): output step for h(t-1) (no dependency on this launch's gemm output).
// mfma_f32_32x32x16_f16: D[row=(reg&3)+8*(reg>>2)+4*(lane>>5)][col=lane&31].
// ---------------------------------------------------------------------------
__global__ __launch_bounds__(256, 2)
void step_fused(const f16* __restrict__ hT_h, const f16* __restrict__ hT_l,
                f16* __restrict__ hTo_h, f16* __restrict__ hTo_l,
                float* __restrict__ c,
                const f16* __restrict__ Wimg_h, const f16* __restrict__ Wimg_l,
                const float* __restrict__ xb,
                const f16* __restrict__ Oh, const f16* __restrict__ Ol,
                const float* __restrict__ b_out,
                float* __restrict__ mask,
                float* __restrict__ msg_p,      // step t-1 outputs
                float* __restrict__ maskout_p,
                float* __restrict__ lp_p,
                const int* __restrict__ eos_ptr,
                int has_out) {
    __shared__ __align__(16) char smem_raw[34048];   // 32 KB B dbuf | 33792 B hstage
    f16* Blds = (f16*)smem_raw;   // row = (buf*16 + sp*8 + ks*4 + g), 512 f16/row

    const int tid  = threadIdx.x;
    const int lane = tid & 63;
    const int wave = tid >> 6;
    const int bid  = blockIdx.x;

    if (bid >= 1024) {              // ---- output-step role (for h(t-1)) ----
        if (!has_out) return;
        int mb = (bid - 1024) * 4 + wave;          // 0..511
        out_body(lane, mb, hT_h, hT_l, Oh, Ol, b_out,
                 mask, msg_p, maskout_p, lp_p, *eos_ptr);
        return;
    }

    // ---- GEMM role ----
    const int wm   = wave;            // compute: m quarter
    const int spw  = wave >> 1;       // staging: split image
    const int ksw  = wave & 1;        // staging: k-sub
    const int jb   = bid >> 6;        // 0..15
    const int mt64 = bid & 63;        // 0..63
    const int mb0  = mt64 * 8;
    const int m0   = mt64 * 256;
    const int j0   = jb * 32;
    const int half = lane >> 5;
    const int l31  = lane & 31;

    f32x16 acc[2][4];
    #pragma unroll
    for (int t = 0; t < 2; t++)
        #pragma unroll
        for (int g = 0; g < 4; g++)
            #pragma unroll
            for (int r = 0; r < 16; r++) acc[t][g][r] = 0.0f;

    const f16* bsrc0 = (spw ? Wimg_l : Wimg_h)
                     + ((size_t)jb * 128 + ksw * 4) * 512 + lane * 8;
    f16* bdst0 = Blds + (size_t)(spw * 8 + ksw * 4) * 512 + lane * 8;

    auto stage_b = [&](int kc, int buf) {
        const f16* s = bsrc0 + (size_t)kc * 4096;
        f16* d = bdst0 + buf * 16 * 512;
        #pragma unroll
        for (int g = 0; g < 4; g++)
            gload16(s + g * 512, d + g * 512);
    };

    const size_t abase0 = ((size_t)mb0 + wm * 2) * 512 + lane * 8;
    auto load_ah = [&](int kc, f16x8 (&dst)[2][2]) {
        #pragma unroll
        for (int ks = 0; ks < 2; ks++)
            #pragma unroll
            for (int t = 0; t < 2; t++)
                dst[ks][t] = *(const f16x8*)(hT_h + abase0
                               + (size_t)(kc * 2 + ks) * (512 * 512) + t * 512);
    };
    auto load_al = [&](int kc, f16x8 (&dst)[2][2]) {
        #pragma unroll
        for (int ks = 0; ks < 2; ks++)
            #pragma unroll
            for (int t = 0; t < 2; t++)
                dst[ks][t] = *(const f16x8*)(hT_l + abase0
                               + (size_t)(kc * 2 + ks) * (512 * 512) + t * 512);
    };

    // pass-major order: same-acc reuse distance = 8 MFMA (dep-chain relief).
    // Per-accumulator accumulation order is unchanged (hh, hl, lh).
    auto compute = [&](f16x8 (&ah)[2][2], f16x8 (&al)[2][2], int buf) {
        #pragma unroll
        for (int ks = 0; ks < 2; ks++) {
            f16x8 bh[4], bl[4];
            #pragma unroll
            for (int g = 0; g < 4; g++) {
                bh[g] = *(const f16x8*)(Blds + (size_t)(buf * 16 + ks * 4 + g) * 512 + lane * 8);
                bl[g] = *(const f16x8*)(Blds + (size_t)(buf * 16 + 8 + ks * 4 + g) * 512 + lane * 8);
            }
            #pragma unroll
            for (int g = 0; g < 4; g++)
                #pragma unroll
                for (int t = 0; t < 2; t++)
                    acc[t][g] = __builtin_amdgcn_mfma_f32_32x32x16_f16(ah[ks][t], bh[g], acc[t][g], 0, 0, 0);
            #pragma unroll
            for (int g = 0; g < 4; g++)
                #pragma unroll
                for (int t = 0; t < 2; t++)
                    acc[t][g] = __builtin_amdgcn_mfma_f32_32x32x16_f16(ah[ks][t], bl[g], acc[t][g], 0, 0, 0);
            #pragma unroll
            for (int g = 0; g < 4; g++)
                #pragma unroll
                for (int t = 0; t < 2; t++)
                    acc[t][g] = __builtin_amdgcn_mfma_f32_32x32x16_f16(al[ks][t], bh[g], acc[t][g], 0, 0, 0);
        }
    };

    f16x8 ah0[2][2], ah1[2][2], al[2][2];
    stage_b(0, 0);
    load_ah(0, ah0);
    for (int kc2 = 0; kc2 < 8; kc2++) {
        const int kc = kc2 * 2;
        __syncthreads();                 // buf0(kc) + ah0 ready (issued 1 chunk ago)
        stage_b(kc + 1, 1);
        load_ah(kc + 1, ah1);
        load_al(kc, al);
        compute(ah0, al, 0);
        __syncthreads();                 // buf1(kc+1) + ah1 ready
        stage_b(kc + 2, 0);              // kc+2==16 on last iter: benign overrun
        load_ah(kc + 2, ah0);
        load_al(kc + 1, al);
        compute(ah1, al, 1);
    }

    // ---- epilogue: cell update + hT-image production via LDS bounce ----
    __syncthreads();
    unsigned int* hstage = (unsigned int*)smem_raw;   // [m:256][j:33] packed (hi,lo)

    const float xbi = xb[0 * HDIM + j0 + l31];
    const float xbf = xb[1 * HDIM + j0 + l31];
    const float xbg = xb[2 * HDIM + j0 + l31];
    const float xbo = xb[3 * HDIM + j0 + l31];
    #pragma unroll
    for (int t = 0; t < 2; t++) {
        #pragma unroll
        for (int reg = 0; reg < 16; reg++) {
            int row = (reg & 3) + 8 * (reg >> 2) + 4 * half;
            int ml  = wm * 64 + t * 32 + row;
            float gi = acc[t][0][reg] * SINV + xbi;
            float gf = acc[t][1][reg] * SINV + xbf;
            float gg = acc[t][2][reg] * SINV + xbg;
            float go = acc[t][3][reg] * SINV + xbo;
            float si = fsig(gi);
            float sf = fsig(gf);
            float tg = ftanh(gg);
            float so = fsig(go);
            size_t idx = (size_t)(m0 + ml) * HDIM + j0 + l31;
            float cn = sf * c[idx] + si * tg;
            c[idx] = cn;
            float hs = so * ftanh(cn) * SH;
            f16 hh = (f16)hs;
            f16 hl = (f16)(hs - (float)hh);
            union { f16 h[2]; unsigned int u; } pk;
            pk.h[0] = hh; pk.h[1] = hl;
            hstage[ml * 33 + l31] = pk.u;
        }
    }
    __syncthreads();

    #pragma unroll
    for (int s = 0; s < 4; s++) {
        int q   = tid + s * 256;
        int ksp = q >> 9;
        int mbl = (q >> 6) & 7;
        int ln  = q & 63;
        int mrow = mbl * 32 + (ln & 31);
        int jj8  = ksp * 16 + (ln >> 5) * 8;
        f16x8 vh, vl;
        #pragma unroll
        for (int i = 0; i < 8; i++) {
            union { unsigned int u; f16 h[2]; } pk;
            pk.u = hstage[mrow * 33 + jj8 + i];
            vh[i] = pk.h[0];
            vl[i] = pk.h[1];
        }
        size_t gq = ((size_t)(jb * 2 + ksp) * 512 + mb0 + mbl) * 64 + ln;
        *(f16x8*)(hTo_h + gq * 8) = vh;
        *(f16x8*)(hTo_l + gq * 8) = vl;
    }
}

// standalone output step (final step only)
__global__ __launch_bounds__(64)
void out_mfma(const f16* __restrict__ hTh, const f16* __restrict__ hTl,
              const f16* __restrict__ Oh, const f16* __restrict__ Ol,
              const float* __restrict__ b_out,
              float* __restrict__ mask,
              float* __restrict__ msg_t,
              float* __restrict__ maskout_t,
              float* __restrict__ lp_part,
              const int* __restrict__ eos_ptr) {
    out_body(threadIdx.x, blockIdx.x, hTh, hTl, Oh, Ol, b_out,
             mask, msg_t, maskout_t, lp_part, *eos_ptr);
}

__global__ void reduce_lp_kernel(const float* __restrict__ parts, int n,
                                 float* __restrict__ out) {
    __shared__ float sm[256];
    float s = 0.0f;
    for (int i = threadIdx.x; i < n; i += 256) s += parts[i];
    sm[threadIdx.x] = s;
    __syncthreads();
    for (int off = 128; off > 0; off >>= 1) {
        if (threadIdx.x < off) sm[threadIdx.x] += sm[threadIdx.x + off];
        __syncthreads();
    }
    if (threadIdx.x == 0) *out = sm[0];
}

// ---------------------------------------------------------------------------
extern "C" void kernel_launch(void* const* d_in, const int* in_sizes, int n_in,
                              void* d_out, int out_size, void* d_ws, size_t ws_size,
                              hipStream_t stream) {
    const float* enc_h  = (const float*)d_in[0];
    const float* enc_c  = (const float*)d_in[1];
    const float* W_ih   = (const float*)d_in[2];
    const float* b_ih   = (const float*)d_in[3];
    const float* W_hh   = (const float*)d_in[4];
    const float* b_hh   = (const float*)d_in[5];
    const float* W_out  = (const float*)d_in[6];
    const float* b_out  = (const float*)d_in[7];
    const float* x0     = (const float*)d_in[8];
    const int*   eosP   = (const int*)d_in[9];

    float* out     = (float*)d_out;
    float* msg     = out;                                   // [20,16384,32]
    float* maskout = out + (size_t)STEPS * BATCH * VOCAB;   // [20,1,16384]
    float* lp_out  = maskout + (size_t)STEPS * BATCH;       // scalar

    const size_t NH = (size_t)BATCH * HDIM;                 // 8388608
    char* w = (char*)d_ws;
    f16* hTh_a = (f16*)w;            w += NH * sizeof(f16);
    f16* hTl_a = (f16*)w;            w += NH * sizeof(f16);
    f16* hTh_b = (f16*)w;            w += NH * sizeof(f16);
    f16* hTl_b = (f16*)w;            w += NH * sizeof(f16);
    float* cbuf = (float*)w;         w += NH * sizeof(float);
    f16* Wimg_h = (f16*)w;           w += (size_t)G4 * HDIM * sizeof(f16);
    f16* Wimg_l = (f16*)w;           w += (size_t)G4 * HDIM * sizeof(f16);
    f16* Wout_h = (f16*)w;           w += (size_t)VOCAB * HDIM * sizeof(f16);
    f16* Wout_l = (f16*)w;           w += (size_t)VOCAB * HDIM * sizeof(f16);
    float* xb = (float*)w;           w += G4 * sizeof(float);
    float* maskbuf = (float*)w;      w += BATCH * sizeof(float);
    float* lp_parts = (float*)w;     // STEPS * 512 floats

    hipMemcpyAsync(cbuf, enc_c, NH * sizeof(float), hipMemcpyDeviceToDevice, stream);
    init_mask_kernel<<<(BATCH + 255) / 256, 256, 0, stream>>>(maskbuf);
    init_xb_kernel<<<(G4 + 255) / 256, 256, 0, stream>>>(W_ih, b_ih, b_hh, x0, xb);
    wimg_kernel<<<(G4 * HDIM / 8) / 256, 256, 0, stream>>>(W_hh, Wimg_h, Wimg_l);
    woutimg_kernel<<<8, 256, 0, stream>>>(W_out, Wout_h, Wout_l);
    hT_init_kernel<<<(int)((NH / 8) / 256), 256, 0, stream>>>(enc_h, hTh_a, hTl_a);

    for (int t = 0; t < STEPS; t++) {
        const f16* hi_in = (t & 1) ? hTh_b : hTh_a;
        const f16* lo_in = (t & 1) ? hTl_b : hTl_a;
        f16* hi_out      = (t & 1) ? hTh_a : hTh_b;
        f16* lo_out      = (t & 1) ? hTl_a : hTl_b;
        int tp = (t > 0) ? (t - 1) : 0;   // previous step (outputs written iff t>0)
        step_fused<<<1152, 256, 0, stream>>>(
            hi_in, lo_in, hi_out, lo_out, cbuf, Wimg_h, Wimg_l, xb,
            Wout_h, Wout_l, b_out, maskbuf,
            msg + (size_t)tp * BATCH * VOCAB,
            maskout + (size_t)tp * BATCH,
            lp_parts + (size_t)tp * 512,
            eosP, t > 0 ? 1 : 0);
    }
    {   // final output step (t = STEPS-1)
        const f16* hi = (STEPS & 1) ? hTh_b : hTh_a;
        const f16* lo = (STEPS & 1) ? hTl_b : hTl_a;
        out_mfma<<<512, 64, 0, stream>>>(
            hi, lo, Wout_h, Wout_l, b_out, maskbuf,
            msg + (size_t)(STEPS - 1) * BATCH * VOCAB,
            maskout + (size_t)(STEPS - 1) * BATCH,
            lp_parts + (size_t)(STEPS - 1) * 512,
            eosP);
    }
    reduce_lp_kernel<<<1, 256, 0, stream>>>(lp_parts, STEPS * 512, lp_out);
}

// Round 8
// 2498.376 us; speedup vs baseline: 1.8505x; 1.0288x over previous
//
#include <hip/hip_runtime.h>
#include <math.h>

#define BATCH 16384
#define HDIM  512
#define VOCAB 32
#define STEPS 20
#define G4    2048

typedef _Float16 f16;
typedef _Float16 f16x8 __attribute__((ext_vector_type(8)));
typedef float    f32x16 __attribute__((ext_vector_type(16)));

#define SH   256.0f            // h pre-scale before fp16 split
#define SW   1024.0f           // W pre-scale before fp16 split
#define SINV (1.0f / (SH * SW))

// Fragment-ordered global images (granule = 16 B = 8 f16 = one lane's A/B frag):
//  hT  [kk:32][mb:512][lane:64]          granule(kk,mb,lane) =
//        h[m = mb*32 + (lane&31)][k = kk*16 + (lane>>5)*8 .. +8]
//  Wimg row r = jb*128 + kc*8 + ks*4 + g, granule(r,lane) =
//        W[n = g*512 + jb*32 + (lane&31)][k = kc*32 + ks*16 + (lane>>5)*8 .. +8]
//  Wout row r = kc*2 + ks (32 rows), granule(r,lane) =
//        W_out[v = lane&31][k = kc*32 + ks*16 + (lane>>5)*8 .. +8]

__device__ __forceinline__ void gload16(const void* g, void* l) {
#if defined(__has_builtin) && __has_builtin(__builtin_amdgcn_global_load_lds)
    __builtin_amdgcn_global_load_lds(
        (const __attribute__((address_space(1))) void*)g,
        (__attribute__((address_space(3))) void*)l, 16, 0, 0);
#else
    *(float4*)l = *(const float4*)g;
#endif
}

__device__ __forceinline__ float fsig(float x)  { return 1.0f / (1.0f + __expf(-x)); }
__device__ __forceinline__ float ftanh(float x) { return 1.0f - 2.0f / (__expf(2.0f * x) + 1.0f); }

// ---------------------------------------------------------------------------
// init / prep kernels (once per launch, outside the step loop)
// ---------------------------------------------------------------------------
__global__ void init_xb_kernel(const float* __restrict__ W_ih,
                               const float* __restrict__ b_ih,
                               const float* __restrict__ b_hh,
                               const float* __restrict__ x0,
                               float* __restrict__ xb) {
    int n = blockIdx.x * blockDim.x + threadIdx.x;
    if (n >= G4) return;
    float s = b_ih[n] + b_hh[n];
    const float* wr = W_ih + (size_t)n * VOCAB;
    #pragma unroll
    for (int v = 0; v < VOCAB; v++) s += wr[v] * x0[v];
    xb[n] = s;
}

__global__ void init_mask_kernel(float* __restrict__ mask) {
    int b = blockIdx.x * blockDim.x + threadIdx.x;
    if (b < BATCH) mask[b] = 1.0f;
}

// W_hh (fp32 [2048][512]) -> fragment-ordered split images (131072 granules)
__global__ void wimg_kernel(const float* __restrict__ W_hh,
                            f16* __restrict__ Wh, f16* __restrict__ Wl) {
    size_t g  = (size_t)blockIdx.x * 256 + threadIdx.x;   // granule id
    int ln = g & 63;  size_t r = g >> 6;                   // r = ((jb*16+kc)*2+ks)*4+gg
    int gg = r & 3;   size_t r2 = r >> 2;
    int ks = r2 & 1;  size_t r3 = r2 >> 1;
    int kc = r3 & 15; int jb = (int)(r3 >> 4);
    int n = gg * 512 + jb * 32 + (ln & 31);
    int k = kc * 32 + ks * 16 + (ln >> 5) * 8;
    const float* s = W_hh + (size_t)n * HDIM + k;
    f16x8 vh, vl;
    #pragma unroll
    for (int i = 0; i < 8; i++) {
        float x = s[i] * SW;
        f16 h = (f16)x;
        vh[i] = h;
        vl[i] = (f16)(x - (float)h);
    }
    *(f16x8*)(Wh + g * 8) = vh;
    *(f16x8*)(Wl + g * 8) = vl;
}

// W_out (fp32 [32][512]) -> fragment-ordered split images (2048 granules)
__global__ void woutimg_kernel(const float* __restrict__ W_out,
                               f16* __restrict__ Oh, f16* __restrict__ Ol) {
    int g  = blockIdx.x * 256 + threadIdx.x;   // 0..2047
    int ln = g & 63;
    int r  = g >> 6;                            // 0..31 = kc*2 + ks
    int kc = r >> 1, ks = r & 1;
    int v  = ln & 31;
    int k  = kc * 32 + ks * 16 + (ln >> 5) * 8;
    const float* s = W_out + (size_t)v * HDIM + k;
    f16x8 vh, vl;
    #pragma unroll
    for (int i = 0; i < 8; i++) {
        float x = s[i] * SW;
        f16 h = (f16)x;
        vh[i] = h;
        vl[i] = (f16)(x - (float)h);
    }
    *(f16x8*)(Oh + (size_t)g * 8) = vh;
    *(f16x8*)(Ol + (size_t)g * 8) = vl;
}

// enc_h (fp32 [16384][512]) -> fragment-ordered split hT images (1048576 granules)
__global__ void hT_init_kernel(const float* __restrict__ src,
                               f16* __restrict__ dh, f16* __restrict__ dl) {
    size_t g = (size_t)blockIdx.x * 256 + threadIdx.x;    // granule id
    int ln = g & 63;  size_t r = g >> 6;                   // r = kk*512 + mb
    int mb = (int)(r & 511); int kk = (int)(r >> 9);
    int m = mb * 32 + (ln & 31);
    int k = kk * 16 + (ln >> 5) * 8;
    const float* s = src + (size_t)m * HDIM + k;
    f16x8 vh, vl;
    #pragma unroll
    for (int i = 0; i < 8; i++) {
        float x = s[i] * SH;
        f16 h = (f16)x;
        vh[i] = h;
        vl[i] = (f16)(x - (float)h);
    }
    *(f16x8*)(dh + g * 8) = vh;
    *(f16x8*)(dl + g * 8) = vl;
}

// ---------------------------------------------------------------------------
// Output-step body: one wave computes logits/argmax/softmax for 32 batch rows.
// No LDS, no barriers.  logits = h @ W_out^T via 3-pass split, frags register-
// loaded from fragment-ordered images (Wout image is 128 KB, L2-resident).
// ---------------------------------------------------------------------------
__device__ __forceinline__ void out_body(int lane, int mb,
        const f16* __restrict__ hTh, const f16* __restrict__ hTl,
        const f16* __restrict__ Oh,  const f16* __restrict__ Ol,
        const float* __restrict__ b_out,
        float* __restrict__ mask, float* __restrict__ msg_t,
        float* __restrict__ maskout_t, float* __restrict__ lp_part, int eos) {
    const int half = lane >> 5;
    const int l31  = lane & 31;

    f32x16 acc;
    #pragma unroll
    for (int r = 0; r < 16; r++) acc[r] = 0.0f;

    f16x8 ah[3][2], al[3][2], bh[3][2], bl[3][2];
    auto load_frags = [&](int kc, int buf) {
        #pragma unroll
        for (int ks = 0; ks < 2; ks++) {
            size_t ga = ((size_t)(kc * 2 + ks) * 512 + mb) * 64 + lane;
            size_t gb = ((size_t)(kc * 2 + ks)) * 64 + lane;
            ah[buf][ks] = *(const f16x8*)(hTh + ga * 8);
            al[buf][ks] = *(const f16x8*)(hTl + ga * 8);
            bh[buf][ks] = *(const f16x8*)(Oh + gb * 8);
            bl[buf][ks] = *(const f16x8*)(Ol + gb * 8);
        }
    };

    load_frags(0, 0);
    load_frags(1, 1);
    for (int kc = 0; kc < 16; kc++) {
        if (kc < 14) load_frags(kc + 2, (kc + 2) % 3);
        int b = kc % 3;
        #pragma unroll
        for (int ks = 0; ks < 2; ks++) {
            acc = __builtin_amdgcn_mfma_f32_32x32x16_f16(ah[b][ks], bh[b][ks], acc, 0, 0, 0);
            acc = __builtin_amdgcn_mfma_f32_32x32x16_f16(ah[b][ks], bl[b][ks], acc, 0, 0, 0);
            acc = __builtin_amdgcn_mfma_f32_32x32x16_f16(al[b][ks], bh[b][ks], acc, 0, 0, 0);
        }
    }

    const float bo = b_out[l31];
    const int   m0 = mb * 32;
    float lpacc = 0.0f;

    #pragma unroll
    for (int reg = 0; reg < 16; reg++) {
        int row = (reg & 3) + 8 * (reg >> 2) + 4 * half;
        int m   = m0 + row;
        float logit = acc[reg] * SINV + bo;

        float mval = logit;
        int   midx = l31;
        #pragma unroll
        for (int off = 16; off > 0; off >>= 1) {
            float ov = __shfl_xor(mval, off, 32);
            int   oi = __shfl_xor(midx, off, 32);
            if (ov > mval || (ov == mval && oi < midx)) { mval = ov; midx = oi; }
        }
        float s = __expf(logit - mval);
        #pragma unroll
        for (int off = 16; off > 0; off >>= 1) s += __shfl_xor(s, off, 32);

        msg_t[(size_t)m * VOCAB + l31] = (l31 == midx) ? 1.0f : 0.0f;
        if (l31 == 0) {
            float mo = mask[m];
            maskout_t[m] = mo;
            lpacc += mo * (-__logf(s));
            if (midx == eos) mask[m] = 0.0f;
        }
    }
    lpacc += __shfl_xor(lpacc, 32);   // fold lane 32's partial into lane 0
    if (lane == 0) lp_part[mb] = lpacc;
}

// ---------------------------------------------------------------------------
// Fused step kernel.  Blocks 0..127 (4 waves each): output step for h(t-1)
// (placed FIRST so the scheduler backfills gemm blocks behind them — no idle
// tail round).  Blocks 128..1151: MFMA GEMM (gates = h(t-1) @ W_hh^T, 3-pass
// fp16 split) + LSTM cell -> h(t) images.
// mfma_f32_32x32x16_f16: D[row=(reg&3)+8*(reg>>2)+4*(lane>>5)][col=lane&31].
// ---------------------------------------------------------------------------
__global__ __launch_bounds__(256, 2)
void step_fused(const f16* __restrict__ hT_h, const f16* __restrict__ hT_l,
                f16* __restrict__ hTo_h, f16* __restrict__ hTo_l,
                float* __restrict__ c,
                const f16* __restrict__ Wimg_h, const f16* __restrict__ Wimg_l,
                const float* __restrict__ xb,
                const f16* __restrict__ Oh, const f16* __restrict__ Ol,
                const float* __restrict__ b_out,
                float* __restrict__ mask,
                float* __restrict__ msg_p,      // step t-1 outputs
                float* __restrict__ maskout_p,
                float* __restrict__ lp_p,
                const int* __restrict__ eos_ptr,
                int has_out) {
    __shared__ __align__(16) char smem_raw[34048];   // 32 KB B dbuf | 33792 B hstage
    f16* Blds = (f16*)smem_raw;   // row = (buf*16 + sp*8 + ks*4 + g), 512 f16/row

    const int tid  = threadIdx.x;
    const int lane = tid & 63;
    const int wave = tid >> 6;
    const int bid  = blockIdx.x;

    if (bid < 128) {                // ---- output-step role (for h(t-1)) ----
        if (!has_out) return;
        int mb = bid * 4 + wave;                   // 0..511
        out_body(lane, mb, hT_h, hT_l, Oh, Ol, b_out,
                 mask, msg_p, maskout_p, lp_p, *eos_ptr);
        return;
    }

    // ---- GEMM role ----
    const int gb   = bid - 128;       // 0..1023
    const int wm   = wave;            // compute: m quarter
    const int spw  = wave >> 1;       // staging: split image
    const int ksw  = wave & 1;        // staging: k-sub
    const int jb   = gb >> 6;         // 0..15
    const int mt64 = gb & 63;         // 0..63
    const int mb0  = mt64 * 8;
    const int m0   = mt64 * 256;
    const int j0   = jb * 32;
    const int half = lane >> 5;
    const int l31  = lane & 31;

    f32x16 acc[2][4];
    #pragma unroll
    for (int t = 0; t < 2; t++)
        #pragma unroll
        for (int g = 0; g < 4; g++)
            #pragma unroll
            for (int r = 0; r < 16; r++) acc[t][g][r] = 0.0f;

    const f16* bsrc0 = (spw ? Wimg_l : Wimg_h)
                     + ((size_t)jb * 128 + ksw * 4) * 512 + lane * 8;
    f16* bdst0 = Blds + (size_t)(spw * 8 + ksw * 4) * 512 + lane * 8;

    auto stage_b = [&](int kc, int buf) {
        const f16* s = bsrc0 + (size_t)kc * 4096;
        f16* d = bdst0 + buf * 16 * 512;
        #pragma unroll
        for (int g = 0; g < 4; g++)
            gload16(s + g * 512, d + g * 512);
    };

    const size_t abase0 = ((size_t)mb0 + wm * 2) * 512 + lane * 8;
    auto load_ah = [&](int kc, f16x8 (&dst)[2][2]) {
        #pragma unroll
        for (int ks = 0; ks < 2; ks++)
            #pragma unroll
            for (int t = 0; t < 2; t++)
                dst[ks][t] = *(const f16x8*)(hT_h + abase0
                               + (size_t)(kc * 2 + ks) * (512 * 512) + t * 512);
    };
    auto load_al = [&](int kc, f16x8 (&dst)[2][2]) {
        #pragma unroll
        for (int ks = 0; ks < 2; ks++)
            #pragma unroll
            for (int t = 0; t < 2; t++)
                dst[ks][t] = *(const f16x8*)(hT_l + abase0
                               + (size_t)(kc * 2 + ks) * (512 * 512) + t * 512);
    };

    // pass-major order: same-acc reuse distance = 8 MFMA.
    // Per-accumulator accumulation order unchanged (hh, hl, lh).
    auto compute = [&](f16x8 (&ah)[2][2], f16x8 (&al)[2][2], int buf) {
        #pragma unroll
        for (int ks = 0; ks < 2; ks++) {
            f16x8 bh[4], bl[4];
            #pragma unroll
            for (int g = 0; g < 4; g++) {
                bh[g] = *(const f16x8*)(Blds + (size_t)(buf * 16 + ks * 4 + g) * 512 + lane * 8);
                bl[g] = *(const f16x8*)(Blds + (size_t)(buf * 16 + 8 + ks * 4 + g) * 512 + lane * 8);
            }
            #pragma unroll
            for (int g = 0; g < 4; g++)
                #pragma unroll
                for (int t = 0; t < 2; t++)
                    acc[t][g] = __builtin_amdgcn_mfma_f32_32x32x16_f16(ah[ks][t], bh[g], acc[t][g], 0, 0, 0);
            #pragma unroll
            for (int g = 0; g < 4; g++)
                #pragma unroll
                for (int t = 0; t < 2; t++)
                    acc[t][g] = __builtin_amdgcn_mfma_f32_32x32x16_f16(ah[ks][t], bl[g], acc[t][g], 0, 0, 0);
            #pragma unroll
            for (int g = 0; g < 4; g++)
                #pragma unroll
                for (int t = 0; t < 2; t++)
                    acc[t][g] = __builtin_amdgcn_mfma_f32_32x32x16_f16(al[ks][t], bh[g], acc[t][g], 0, 0, 0);
        }
    };

    // A-hi AND A-lo both prefetched one chunk ahead (al stall relief).
    f16x8 ah0[2][2], ah1[2][2], al0[2][2], al1[2][2];
    stage_b(0, 0);
    load_ah(0, ah0);
    load_al(0, al0);
    for (int kc2 = 0; kc2 < 8; kc2++) {
        const int kc = kc2 * 2;
        __syncthreads();                 // buf0(kc) + ah0/al0 ready (issued 1 chunk ago)
        stage_b(kc + 1, 1);
        load_ah(kc + 1, ah1);
        load_al(kc + 1, al1);
        compute(ah0, al0, 0);
        __syncthreads();                 // buf1(kc+1) + ah1/al1 ready
        stage_b(kc + 2, 0);              // kc+2==16 on last iter: benign overrun
        load_ah(kc + 2, ah0);            //   (reads stay inside workspace)
        load_al(kc + 2, al0);
        compute(ah1, al1, 1);
    }

    // ---- epilogue: cell update + hT-image production via LDS bounce ----
    __syncthreads();
    unsigned int* hstage = (unsigned int*)smem_raw;   // [m:256][j:33] packed (hi,lo)

    const float xbi = xb[0 * HDIM + j0 + l31];
    const float xbf = xb[1 * HDIM + j0 + l31];
    const float xbg = xb[2 * HDIM + j0 + l31];
    const float xbo = xb[3 * HDIM + j0 + l31];
    #pragma unroll
    for (int t = 0; t < 2; t++) {
        #pragma unroll
        for (int reg = 0; reg < 16; reg++) {
            int row = (reg & 3) + 8 * (reg >> 2) + 4 * half;
            int ml  = wm * 64 + t * 32 + row;
            float gi = acc[t][0][reg] * SINV + xbi;
            float gf = acc[t][1][reg] * SINV + xbf;
            float gg = acc[t][2][reg] * SINV + xbg;
            float go = acc[t][3][reg] * SINV + xbo;
            float si = fsig(gi);
            float sf = fsig(gf);
            float tg = ftanh(gg);
            float so = fsig(go);
            size_t idx = (size_t)(m0 + ml) * HDIM + j0 + l31;
            float cn = sf * c[idx] + si * tg;
            c[idx] = cn;
            float hs = so * ftanh(cn) * SH;
            f16 hh = (f16)hs;
            f16 hl = (f16)(hs - (float)hh);
            union { f16 h[2]; unsigned int u; } pk;
            pk.h[0] = hh; pk.h[1] = hl;
            hstage[ml * 33 + l31] = pk.u;
        }
    }
    __syncthreads();

    #pragma unroll
    for (int s = 0; s < 4; s++) {
        int q   = tid + s * 256;
        int ksp = q >> 9;
        int mbl = (q >> 6) & 7;
        int ln  = q & 63;
        int mrow = mbl * 32 + (ln & 31);
        int jj8  = ksp * 16 + (ln >> 5) * 8;
        f16x8 vh, vl;
        #pragma unroll
        for (int i = 0; i < 8; i++) {
            union { unsigned int u; f16 h[2]; } pk;
            pk.u = hstage[mrow * 33 + jj8 + i];
            vh[i] = pk.h[0];
            vl[i] = pk.h[1];
        }
        size_t gq = ((size_t)(jb * 2 + ksp) * 512 + mb0 + mbl) * 64 + ln;
        *(f16x8*)(hTo_h + gq * 8) = vh;
        *(f16x8*)(hTo_l + gq * 8) = vl;
    }
}

// standalone output step (final step only)
__global__ __launch_bounds__(64)
void out_mfma(const f16* __restrict__ hTh, const f16* __restrict__ hTl,
              const f16* __restrict__ Oh, const f16* __restrict__ Ol,
              const float* __restrict__ b_out,
              float* __restrict__ mask,
              float* __restrict__ msg_t,
              float* __restrict__ maskout_t,
              float* __restrict__ lp_part,
              const int* __restrict__ eos_ptr) {
    out_body(threadIdx.x, blockIdx.x, hTh, hTl, Oh, Ol, b_out,
             mask, msg_t, maskout_t, lp_part, *eos_ptr);
}

__global__ void reduce_lp_kernel(const float* __restrict__ parts, int n,
                                 float* __restrict__ out) {
    __shared__ float sm[256];
    float s = 0.0f;
    for (int i = threadIdx.x; i < n; i += 256) s += parts[i];
    sm[threadIdx.x] = s;
    __syncthreads();
    for (int off = 128; off > 0; off >>= 1) {
        if (threadIdx.x < off) sm[threadIdx.x] += sm[threadIdx.x + off];
        __syncthreads();
    }
    if (threadIdx.x == 0) *out = sm[0];
}

// ---------------------------------------------------------------------------
extern "C" void kernel_launch(void* const* d_in, const int* in_sizes, int n_in,
                              void* d_out, int out_size, void* d_ws, size_t ws_size,
                              hipStream_t stream) {
    const float* enc_h  = (const float*)d_in[0];
    const float* enc_c  = (const float*)d_in[1];
    const float* W_ih   = (const float*)d_in[2];
    const float* b_ih   = (const float*)d_in[3];
    const float* W_hh   = (const float*)d_in[4];
    const float* b_hh   = (const float*)d_in[5];
    const float* W_out  = (const float*)d_in[6];
    const float* b_out  = (const float*)d_in[7];
    const float* x0     = (const float*)d_in[8];
    const int*   eosP   = (const int*)d_in[9];

    float* out     = (float*)d_out;
    float* msg     = out;                                   // [20,16384,32]
    float* maskout = out + (size_t)STEPS * BATCH * VOCAB;   // [20,1,16384]
    float* lp_out  = maskout + (size_t)STEPS * BATCH;       // scalar

    const size_t NH = (size_t)BATCH * HDIM;                 // 8388608
    char* w = (char*)d_ws;
    f16* hTh_a = (f16*)w;            w += NH * sizeof(f16);
    f16* hTl_a = (f16*)w;            w += NH * sizeof(f16);
    f16* hTh_b = (f16*)w;            w += NH * sizeof(f16);
    f16* hTl_b = (f16*)w;            w += NH * sizeof(f16);
    float* cbuf = (float*)w;         w += NH * sizeof(float);
    f16* Wimg_h = (f16*)w;           w += (size_t)G4 * HDIM * sizeof(f16);
    f16* Wimg_l = (f16*)w;           w += (size_t)G4 * HDIM * sizeof(f16);
    f16* Wout_h = (f16*)w;           w += (size_t)VOCAB * HDIM * sizeof(f16);
    f16* Wout_l = (f16*)w;           w += (size_t)VOCAB * HDIM * sizeof(f16);
    float* xb = (float*)w;           w += G4 * sizeof(float);
    float* maskbuf = (float*)w;      w += BATCH * sizeof(float);
    float* lp_parts = (float*)w;     // STEPS * 512 floats

    hipMemcpyAsync(cbuf, enc_c, NH * sizeof(float), hipMemcpyDeviceToDevice, stream);
    init_mask_kernel<<<(BATCH + 255) / 256, 256, 0, stream>>>(maskbuf);
    init_xb_kernel<<<(G4 + 255) / 256, 256, 0, stream>>>(W_ih, b_ih, b_hh, x0, xb);
    wimg_kernel<<<(G4 * HDIM / 8) / 256, 256, 0, stream>>>(W_hh, Wimg_h, Wimg_l);
    woutimg_kernel<<<8, 256, 0, stream>>>(W_out, Wout_h, Wout_l);
    hT_init_kernel<<<(int)((NH / 8) / 256), 256, 0, stream>>>(enc_h, hTh_a, hTl_a);

    for (int t = 0; t < STEPS; t++) {
        const f16* hi_in = (t & 1) ? hTh_b : hTh_a;
        const f16* lo_in = (t & 1) ? hTl_b : hTl_a;
        f16* hi_out      = (t & 1) ? hTh_a : hTh_b;
        f16* lo_out      = (t & 1) ? hTl_a : hTl_b;
        int tp = (t > 0) ? (t - 1) : 0;   // previous step (outputs written iff t>0)
        step_fused<<<1152, 256, 0, stream>>>(
            hi_in, lo_in, hi_out, lo_out, cbuf, Wimg_h, Wimg_l, xb,
            Wout_h, Wout_l, b_out, maskbuf,
            msg + (size_t)tp * BATCH * VOCAB,
            maskout + (size_t)tp * BATCH,
            lp_parts + (size_t)tp * 512,
            eosP, t > 0 ? 1 : 0);
    }
    {   // final output step (t = STEPS-1)
        const f16* hi = (STEPS & 1) ? hTh_b : hTh_a;
        const f16* lo = (STEPS & 1) ? hTl_b : hTl_a;
        out_mfma<<<512, 64, 0, stream>>>(
            hi, lo, Wout_h, Wout_l, b_out, maskbuf,
            msg + (size_t)(STEPS - 1) * BATCH * VOCAB,
            maskout + (size_t)(STEPS - 1) * BATCH,
            lp_parts + (size_t)(STEPS - 1) * 512,
            eosP);
    }
    reduce_lp_kernel<<<1, 256, 0, stream>>>(lp_parts, STEPS * 512, lp_out);
}

// Round 9
// 2492.070 us; speedup vs baseline: 1.8552x; 1.0025x over previous
//
#include <hip/hip_runtime.h>
#include <math.h>

#define BATCH 16384
#define HDIM  512
#define VOCAB 32
#define STEPS 20
#define G4    2048

typedef _Float16 f16;
typedef _Float16 f16x8 __attribute__((ext_vector_type(8)));
typedef float    f32x16 __attribute__((ext_vector_type(16)));

#define SH   256.0f            // h pre-scale before fp16 split
#define SW   1024.0f           // W pre-scale before fp16 split
#define SINV (1.0f / (SH * SW))

// Fragment-ordered global images (granule = 16 B = 8 f16 = one lane's A/B frag):
//  hT  [kk:32][mb:512][lane:64]          granule(kk,mb,lane) =
//        h[m = mb*32 + (lane&31)][k = kk*16 + (lane>>5)*8 .. +8]
//  Wimg row r = jb*128 + kc*8 + ks*4 + g, granule(r,lane) =
//        W[n = g*512 + jb*32 + (lane&31)][k = kc*32 + ks*16 + (lane>>5)*8 .. +8]
//  Wout row r = kc*2 + ks (32 rows), granule(r,lane) =
//        W_out[v = lane&31][k = kc*32 + ks*16 + (lane>>5)*8 .. +8]

__device__ __forceinline__ void gload16(const void* g, void* l) {
#if defined(__has_builtin) && __has_builtin(__builtin_amdgcn_global_load_lds)
    __builtin_amdgcn_global_load_lds(
        (const __attribute__((address_space(1))) void*)g,
        (__attribute__((address_space(3))) void*)l, 16, 0, 0);
#else
    *(float4*)l = *(const float4*)g;
#endif
}

__device__ __forceinline__ float fsig(float x)  { return 1.0f / (1.0f + __expf(-x)); }
__device__ __forceinline__ float ftanh(float x) { return 1.0f - 2.0f / (__expf(2.0f * x) + 1.0f); }

// ---------------------------------------------------------------------------
// init / prep kernels (once per launch, outside the step loop)
// ---------------------------------------------------------------------------
__global__ void init_xb_kernel(const float* __restrict__ W_ih,
                               const float* __restrict__ b_ih,
                               const float* __restrict__ b_hh,
                               const float* __restrict__ x0,
                               float* __restrict__ xb) {
    int n = blockIdx.x * blockDim.x + threadIdx.x;
    if (n >= G4) return;
    float s = b_ih[n] + b_hh[n];
    const float* wr = W_ih + (size_t)n * VOCAB;
    #pragma unroll
    for (int v = 0; v < VOCAB; v++) s += wr[v] * x0[v];
    xb[n] = s;
}

__global__ void init_mask_kernel(float* __restrict__ mask) {
    int b = blockIdx.x * blockDim.x + threadIdx.x;
    if (b < BATCH) mask[b] = 1.0f;
}

// W_hh (fp32 [2048][512]) -> fragment-ordered split images (131072 granules)
__global__ void wimg_kernel(const float* __restrict__ W_hh,
                            f16* __restrict__ Wh, f16* __restrict__ Wl) {
    size_t g  = (size_t)blockIdx.x * 256 + threadIdx.x;   // granule id
    int ln = g & 63;  size_t r = g >> 6;                   // r = ((jb*16+kc)*2+ks)*4+gg
    int gg = r & 3;   size_t r2 = r >> 2;
    int ks = r2 & 1;  size_t r3 = r2 >> 1;
    int kc = r3 & 15; int jb = (int)(r3 >> 4);
    int n = gg * 512 + jb * 32 + (ln & 31);
    int k = kc * 32 + ks * 16 + (ln >> 5) * 8;
    const float* s = W_hh + (size_t)n * HDIM + k;
    f16x8 vh, vl;
    #pragma unroll
    for (int i = 0; i < 8; i++) {
        float x = s[i] * SW;
        f16 h = (f16)x;
        vh[i] = h;
        vl[i] = (f16)(x - (float)h);
    }
    *(f16x8*)(Wh + g * 8) = vh;
    *(f16x8*)(Wl + g * 8) = vl;
}

// W_out (fp32 [32][512]) -> fragment-ordered split images (2048 granules)
__global__ void woutimg_kernel(const float* __restrict__ W_out,
                               f16* __restrict__ Oh, f16* __restrict__ Ol) {
    int g  = blockIdx.x * 256 + threadIdx.x;   // 0..2047
    int ln = g & 63;
    int r  = g >> 6;                            // 0..31 = kc*2 + ks
    int kc = r >> 1, ks = r & 1;
    int v  = ln & 31;
    int k  = kc * 32 + ks * 16 + (ln >> 5) * 8;
    const float* s = W_out + (size_t)v * HDIM + k;
    f16x8 vh, vl;
    #pragma unroll
    for (int i = 0; i < 8; i++) {
        float x = s[i] * SW;
        f16 h = (f16)x;
        vh[i] = h;
        vl[i] = (f16)(x - (float)h);
    }
    *(f16x8*)(Oh + (size_t)g * 8) = vh;
    *(f16x8*)(Ol + (size_t)g * 8) = vl;
}

// enc_h (fp32 [16384][512]) -> fragment-ordered split hT images (1048576 granules)
__global__ void hT_init_kernel(const float* __restrict__ src,
                               f16* __restrict__ dh, f16* __restrict__ dl) {
    size_t g = (size_t)blockIdx.x * 256 + threadIdx.x;    // granule id
    int ln = g & 63;  size_t r = g >> 6;                   // r = kk*512 + mb
    int mb = (int)(r & 511); int kk = (int)(r >> 9);
    int m = mb * 32 + (ln & 31);
    int k = kk * 16 + (ln >> 5) * 8;
    const float* s = src + (size_t)m * HDIM + k;
    f16x8 vh, vl;
    #pragma unroll
    for (int i = 0; i < 8; i++) {
        float x = s[i] * SH;
        f16 h = (f16)x;
        vh[i] = h;
        vl[i] = (f16)(x - (float)h);
    }
    *(f16x8*)(dh + g * 8) = vh;
    *(f16x8*)(dl + g * 8) = vl;
}

// ---------------------------------------------------------------------------
// Output-step body: one wave computes logits/argmax/softmax for 32 batch rows.
// No LDS, no barriers.
// ---------------------------------------------------------------------------
__device__ __forceinline__ void out_body(int lane, int mb,
        const f16* __restrict__ hTh, const f16* __restrict__ hTl,
        const f16* __restrict__ Oh,  const f16* __restrict__ Ol,
        const float* __restrict__ b_out,
        float* __restrict__ mask, float* __restrict__ msg_t,
        float* __restrict__ maskout_t, float* __restrict__ lp_part, int eos) {
    const int half = lane >> 5;
    const int l31  = lane & 31;

    f32x16 acc;
    #pragma unroll
    for (int r = 0; r < 16; r++) acc[r] = 0.0f;

    f16x8 ah[3][2], al[3][2], bh[3][2], bl[3][2];
    auto load_frags = [&](int kc, int buf) {
        #pragma unroll
        for (int ks = 0; ks < 2; ks++) {
            size_t ga = ((size_t)(kc * 2 + ks) * 512 + mb) * 64 + lane;
            size_t gb = ((size_t)(kc * 2 + ks)) * 64 + lane;
            ah[buf][ks] = *(const f16x8*)(hTh + ga * 8);
            al[buf][ks] = *(const f16x8*)(hTl + ga * 8);
            bh[buf][ks] = *(const f16x8*)(Oh + gb * 8);
            bl[buf][ks] = *(const f16x8*)(Ol + gb * 8);
        }
    };

    load_frags(0, 0);
    load_frags(1, 1);
    for (int kc = 0; kc < 16; kc++) {
        if (kc < 14) load_frags(kc + 2, (kc + 2) % 3);
        int b = kc % 3;
        #pragma unroll
        for (int ks = 0; ks < 2; ks++) {
            acc = __builtin_amdgcn_mfma_f32_32x32x16_f16(ah[b][ks], bh[b][ks], acc, 0, 0, 0);
            acc = __builtin_amdgcn_mfma_f32_32x32x16_f16(ah[b][ks], bl[b][ks], acc, 0, 0, 0);
            acc = __builtin_amdgcn_mfma_f32_32x32x16_f16(al[b][ks], bh[b][ks], acc, 0, 0, 0);
        }
    }

    const float bo = b_out[l31];
    const int   m0 = mb * 32;
    float lpacc = 0.0f;

    #pragma unroll
    for (int reg = 0; reg < 16; reg++) {
        int row = (reg & 3) + 8 * (reg >> 2) + 4 * half;
        int m   = m0 + row;
        float logit = acc[reg] * SINV + bo;

        float mval = logit;
        int   midx = l31;
        #pragma unroll
        for (int off = 16; off > 0; off >>= 1) {
            float ov = __shfl_xor(mval, off, 32);
            int   oi = __shfl_xor(midx, off, 32);
            if (ov > mval || (ov == mval && oi < midx)) { mval = ov; midx = oi; }
        }
        float s = __expf(logit - mval);
        #pragma unroll
        for (int off = 16; off > 0; off >>= 1) s += __shfl_xor(s, off, 32);

        msg_t[(size_t)m * VOCAB + l31] = (l31 == midx) ? 1.0f : 0.0f;
        if (l31 == 0) {
            float mo = mask[m];
            maskout_t[m] = mo;
            lpacc += mo * (-__logf(s));
            if (midx == eos) mask[m] = 0.0f;
        }
    }
    lpacc += __shfl_xor(lpacc, 32);   // fold lane 32's partial into lane 0
    if (lane == 0) lp_part[mb] = lpacc;
}

// ---------------------------------------------------------------------------
// Fused step kernel.  Blocks 0..127 (4 waves each): output step for h(t-1),
// placed FIRST so gemm blocks backfill behind them.  Blocks 128..2175: MFMA
// GEMM (3-pass fp16 split) + LSTM cell -> h(t) images.
// Block tile 128m x 128n; wave tile 32m x 128n (acc = 64 AGPR -> 3 waves/SIMD).
// Swizzle: jb = gb&15 fastest, so the 16 blocks sharing an A-slice dispatch
// adjacently (A-slice stays L2-hot).
// mfma_f32_32x32x16_f16: D[row=(reg&3)+8*(reg>>2)+4*(lane>>5)][col=lane&31].
// ---------------------------------------------------------------------------
__global__ __launch_bounds__(256, 3)
void step_fused(const f16* __restrict__ hT_h, const f16* __restrict__ hT_l,
                f16* __restrict__ hTo_h, f16* __restrict__ hTo_l,
                float* __restrict__ c,
                const f16* __restrict__ Wimg_h, const f16* __restrict__ Wimg_l,
                const float* __restrict__ xb,
                const f16* __restrict__ Oh, const f16* __restrict__ Ol,
                const float* __restrict__ b_out,
                float* __restrict__ mask,
                float* __restrict__ msg_p,      // step t-1 outputs
                float* __restrict__ maskout_p,
                float* __restrict__ lp_p,
                const int* __restrict__ eos_ptr,
                int has_out) {
    __shared__ __align__(16) char smem_raw[34048];   // 32 KB B dbuf | 16.9 KB hstage
    f16* Blds = (f16*)smem_raw;   // row = (buf*16 + sp*8 + ks*4 + g), 512 f16/row

    const int tid  = threadIdx.x;
    const int lane = tid & 63;
    const int wave = tid >> 6;
    const int bid  = blockIdx.x;

    if (bid < 128) {                // ---- output-step role (for h(t-1)) ----
        if (!has_out) return;
        int mb = bid * 4 + wave;                   // 0..511
        out_body(lane, mb, hT_h, hT_l, Oh, Ol, b_out,
                 mask, msg_p, maskout_p, lp_p, *eos_ptr);
        return;
    }

    // ---- GEMM role ----
    const int gb   = bid - 128;       // 0..2047
    const int jb   = gb & 15;         // n-slice (fastest -> A-slice L2 reuse)
    const int mt   = gb >> 4;         // 0..127, 128-m tile
    const int spw  = wave >> 1;       // staging: split image
    const int ksw  = wave & 1;        // staging: k-sub
    const int mbA  = mt * 4 + wave;   // this wave's 32-m granule row
    const int m0   = mt * 128;
    const int j0   = jb * 32;
    const int half = lane >> 5;
    const int l31  = lane & 31;

    f32x16 acc[4];                    // [gate] for this wave's 32m x 32j
    #pragma unroll
    for (int g = 0; g < 4; g++)
        #pragma unroll
        for (int r = 0; r < 16; r++) acc[g][r] = 0.0f;

    const f16* bsrc0 = (spw ? Wimg_l : Wimg_h)
                     + ((size_t)jb * 128 + ksw * 4) * 512 + lane * 8;
    f16* bdst0 = Blds + (size_t)(spw * 8 + ksw * 4) * 512 + lane * 8;

    auto stage_b = [&](int kc, int buf) {
        const f16* s = bsrc0 + (size_t)kc * 4096;
        f16* d = bdst0 + buf * 16 * 512;
        #pragma unroll
        for (int g = 0; g < 4; g++)
            gload16(s + g * 512, d + g * 512);
    };

    const size_t abase0 = (size_t)mbA * 512 + lane * 8;
    auto load_ah = [&](int kc, f16x8 (&dst)[2]) {
        #pragma unroll
        for (int ks = 0; ks < 2; ks++)
            dst[ks] = *(const f16x8*)(hT_h + abase0
                           + (size_t)(kc * 2 + ks) * (512 * 512));
    };
    auto load_al = [&](int kc, f16x8 (&dst)[2]) {
        #pragma unroll
        for (int ks = 0; ks < 2; ks++)
            dst[ks] = *(const f16x8*)(hT_l + abase0
                           + (size_t)(kc * 2 + ks) * (512 * 512));
    };

    // pass-major order; per-accumulator accumulation order (hh, hl, lh) is
    // unchanged from prior rounds -> bit-identical results.
    auto compute = [&](f16x8 (&ah)[2], f16x8 (&al)[2], int buf) {
        #pragma unroll
        for (int ks = 0; ks < 2; ks++) {
            f16x8 bh[4], bl[4];
            #pragma unroll
            for (int g = 0; g < 4; g++) {
                bh[g] = *(const f16x8*)(Blds + (size_t)(buf * 16 + ks * 4 + g) * 512 + lane * 8);
                bl[g] = *(const f16x8*)(Blds + (size_t)(buf * 16 + 8 + ks * 4 + g) * 512 + lane * 8);
            }
            #pragma unroll
            for (int g = 0; g < 4; g++)
                acc[g] = __builtin_amdgcn_mfma_f32_32x32x16_f16(ah[ks], bh[g], acc[g], 0, 0, 0);
            #pragma unroll
            for (int g = 0; g < 4; g++)
                acc[g] = __builtin_amdgcn_mfma_f32_32x32x16_f16(ah[ks], bl[g], acc[g], 0, 0, 0);
            #pragma unroll
            for (int g = 0; g < 4; g++)
                acc[g] = __builtin_amdgcn_mfma_f32_32x32x16_f16(al[ks], bh[g], acc[g], 0, 0, 0);
        }
    };

    f16x8 ah0[2], ah1[2], al0[2], al1[2];
    stage_b(0, 0);
    load_ah(0, ah0);
    load_al(0, al0);
    for (int kc2 = 0; kc2 < 8; kc2++) {
        const int kc = kc2 * 2;
        __syncthreads();                 // buf0(kc) + ah0/al0 ready (issued 1 chunk ago)
        stage_b(kc + 1, 1);
        load_ah(kc + 1, ah1);
        load_al(kc + 1, al1);
        compute(ah0, al0, 0);
        __syncthreads();                 // buf1(kc+1) + ah1/al1 ready
        stage_b(kc + 2, 0);              // kc+2==16 on last iter: benign overrun
        load_ah(kc + 2, ah0);            //   (reads stay inside workspace)
        load_al(kc + 2, al0);
        compute(ah1, al1, 1);
    }

    // ---- epilogue: cell update + hT-image production via LDS bounce ----
    __syncthreads();
    unsigned int* hstage = (unsigned int*)smem_raw;   // [m:128][j:33] packed (hi,lo)

    const float xbi = xb[0 * HDIM + j0 + l31];
    const float xbf = xb[1 * HDIM + j0 + l31];
    const float xbg = xb[2 * HDIM + j0 + l31];
    const float xbo = xb[3 * HDIM + j0 + l31];
    #pragma unroll
    for (int reg = 0; reg < 16; reg++) {
        int row = (reg & 3) + 8 * (reg >> 2) + 4 * half;
        int ml  = wave * 32 + row;                 // local m (0..127)
        float gi = acc[0][reg] * SINV + xbi;
        float gf = acc[1][reg] * SINV + xbf;
        float gg = acc[2][reg] * SINV + xbg;
        float go = acc[3][reg] * SINV + xbo;
        float si = fsig(gi);
        float sf = fsig(gf);
        float tg = ftanh(gg);
        float so = fsig(go);
        size_t idx = (size_t)(m0 + ml) * HDIM + j0 + l31;
        float cn = sf * c[idx] + si * tg;
        c[idx] = cn;
        float hs = so * ftanh(cn) * SH;
        f16 hh = (f16)hs;
        f16 hl = (f16)(hs - (float)hh);
        union { f16 h[2]; unsigned int u; } pk;
        pk.h[0] = hh; pk.h[1] = hl;
        hstage[ml * 33 + l31] = pk.u;
    }
    __syncthreads();

    // emit 512 granules: q = (ksp<<8)|(mbl<<6)|ln
    #pragma unroll
    for (int s = 0; s < 2; s++) {
        int q   = tid + s * 256;
        int ksp = q >> 8;
        int mbl = (q >> 6) & 3;
        int ln  = q & 63;
        int mrow = mbl * 32 + (ln & 31);           // local m (0..127)
        int jj8  = ksp * 16 + (ln >> 5) * 8;
        f16x8 vh, vl;
        #pragma unroll
        for (int i = 0; i < 8; i++) {
            union { unsigned int u; f16 h[2]; } pk;
            pk.u = hstage[mrow * 33 + jj8 + i];
            vh[i] = pk.h[0];
            vl[i] = pk.h[1];
        }
        size_t gq = ((size_t)(jb * 2 + ksp) * 512 + mt * 4 + mbl) * 64 + ln;
        *(f16x8*)(hTo_h + gq * 8) = vh;
        *(f16x8*)(hTo_l + gq * 8) = vl;
    }
}

// standalone output step (final step only)
__global__ __launch_bounds__(64)
void out_mfma(const f16* __restrict__ hTh, const f16* __restrict__ hTl,
              const f16* __restrict__ Oh, const f16* __restrict__ Ol,
              const float* __restrict__ b_out,
              float* __restrict__ mask,
              float* __restrict__ msg_t,
              float* __restrict__ maskout_t,
              float* __restrict__ lp_part,
              const int* __restrict__ eos_ptr) {
    out_body(threadIdx.x, blockIdx.x, hTh, hTl, Oh, Ol, b_out,
             mask, msg_t, maskout_t, lp_part, *eos_ptr);
}

__global__ void reduce_lp_kernel(const float* __restrict__ parts, int n,
                                 float* __restrict__ out) {
    __shared__ float sm[256];
    float s = 0.0f;
    for (int i = threadIdx.x; i < n; i += 256) s += parts[i];
    sm[threadIdx.x] = s;
    __syncthreads();
    for (int off = 128; off > 0; off >>= 1) {
        if (threadIdx.x < off) sm[threadIdx.x] += sm[threadIdx.x + off];
        __syncthreads();
    }
    if (threadIdx.x == 0) *out = sm[0];
}

// ---------------------------------------------------------------------------
extern "C" void kernel_launch(void* const* d_in, const int* in_sizes, int n_in,
                              void* d_out, int out_size, void* d_ws, size_t ws_size,
                              hipStream_t stream) {
    const float* enc_h  = (const float*)d_in[0];
    const float* enc_c  = (const float*)d_in[1];
    const float* W_ih   = (const float*)d_in[2];
    const float* b_ih   = (const float*)d_in[3];
    const float* W_hh   = (const float*)d_in[4];
    const float* b_hh   = (const float*)d_in[5];
    const float* W_out  = (const float*)d_in[6];
    const float* b_out  = (const float*)d_in[7];
    const float* x0     = (const float*)d_in[8];
    const int*   eosP   = (const int*)d_in[9];

    float* out     = (float*)d_out;
    float* msg     = out;                                   // [20,16384,32]
    float* maskout = out + (size_t)STEPS * BATCH * VOCAB;   // [20,1,16384]
    float* lp_out  = maskout + (size_t)STEPS * BATCH;       // scalar

    const size_t NH = (size_t)BATCH * HDIM;                 // 8388608
    char* w = (char*)d_ws;
    f16* hTh_a = (f16*)w;            w += NH * sizeof(f16);
    f16* hTl_a = (f16*)w;            w += NH * sizeof(f16);
    f16* hTh_b = (f16*)w;            w += NH * sizeof(f16);
    f16* hTl_b = (f16*)w;            w += NH * sizeof(f16);
    float* cbuf = (float*)w;         w += NH * sizeof(float);
    f16* Wimg_h = (f16*)w;           w += (size_t)G4 * HDIM * sizeof(f16);
    f16* Wimg_l = (f16*)w;           w += (size_t)G4 * HDIM * sizeof(f16);
    f16* Wout_h = (f16*)w;           w += (size_t)VOCAB * HDIM * sizeof(f16);
    f16* Wout_l = (f16*)w;           w += (size_t)VOCAB * HDIM * sizeof(f16);
    float* xb = (float*)w;           w += G4 * sizeof(float);
    float* maskbuf = (float*)w;      w += BATCH * sizeof(float);
    float* lp_parts = (float*)w;     // STEPS * 512 floats

    hipMemcpyAsync(cbuf, enc_c, NH * sizeof(float), hipMemcpyDeviceToDevice, stream);
    init_mask_kernel<<<(BATCH + 255) / 256, 256, 0, stream>>>(maskbuf);
    init_xb_kernel<<<(G4 + 255) / 256, 256, 0, stream>>>(W_ih, b_ih, b_hh, x0, xb);
    wimg_kernel<<<(G4 * HDIM / 8) / 256, 256, 0, stream>>>(W_hh, Wimg_h, Wimg_l);
    woutimg_kernel<<<8, 256, 0, stream>>>(W_out, Wout_h, Wout_l);
    hT_init_kernel<<<(int)((NH / 8) / 256), 256, 0, stream>>>(enc_h, hTh_a, hTl_a);

    for (int t = 0; t < STEPS; t++) {
        const f16* hi_in = (t & 1) ? hTh_b : hTh_a;
        const f16* lo_in = (t & 1) ? hTl_b : hTl_a;
        f16* hi_out      = (t & 1) ? hTh_a : hTh_b;
        f16* lo_out      = (t & 1) ? hTl_a : hTl_b;
        int tp = (t > 0) ? (t - 1) : 0;   // previous step (outputs written iff t>0)
        step_fused<<<2176, 256, 0, stream>>>(
            hi_in, lo_in, hi_out, lo_out, cbuf, Wimg_h, Wimg_l, xb,
            Wout_h, Wout_l, b_out, maskbuf,
            msg + (size_t)tp * BATCH * VOCAB,
            maskout + (size_t)tp * BATCH,
            lp_parts + (size_t)tp * 512,
            eosP, t > 0 ? 1 : 0);
    }
    {   // final output step (t = STEPS-1)
        const f16* hi = (STEPS & 1) ? hTh_b : hTh_a;
        const f16* lo = (STEPS & 1) ? hTl_b : hTl_a;
        out_mfma<<<512, 64, 0, stream>>>(
            hi, lo, Wout_h, Wout_l, b_out, maskbuf,
            msg + (size_t)(STEPS - 1) * BATCH * VOCAB,
            maskout + (size_t)(STEPS - 1) * BATCH,
            lp_parts + (size_t)(STEPS - 1) * 512,
            eosP);
    }
    reduce_lp_kernel<<<1, 256, 0, stream>>>(lp_parts, STEPS * 512, lp_out);
}